// Round 7
// baseline (547.274 us; speedup 1.0000x reference)
//
#include <hip/hip_runtime.h>
#include <hip/hip_bf16.h>

// minLSTM: pre = x @ W^T + b (M=32768, N=1536, K=512), log-space gates,
// chunked log-space scan over L=4096 per (n,h), out = exp(log_h).
// ALL log-domain values are in LOG2 units (v_exp/v_log are base-2 native).
// Gate math: sigma-sum identity (3 exp + 4 log per position).
// SINGLE-PASS: gemm_gates computes GEMM, gates, per-chunk scan AND the
// cross-chunk carry via decoupled lookback, then writes exp2(log_h)
// directly (no plv round-trip: saves 128 MB HBM + a kernel).
// LOOKBACK (v2, parallel): blocks publish ONLY chunk aggregates (flag=1,
// available right after each block's epilogue -> all payloads appear
// ~simultaneously). All 4 waves fold disjoint contiguous quarters of the
// <=31 predecessors in parallel (<=8 serial folds each), segment products
// combined in LDS (3 folds). Serial depth 31 -> 11. Round-6's serial
// inclusive-forwarding lookback (depth 31 x ~2.5us, per residency batch)
// was the 377us failure -- do not bring back.
// Deadlock-free: block (by,bx) waits only on same-bx lower-by = strictly
// lower linear IDs (dispatched earlier). Flags zeroed via memsetAsync.
// Rounds 2-4 falsified: any fp32-A-in-GEMM scheme loses more than the
// 2-pass convert costs. Do not revisit.

#define H_DIM 512
#define LSEQ 4096
#define NBATCH 8
#define M_TOTAL (NBATCH * LSEQ)  // 32768

#define BM 128
#define BK 64

#define CS 128
#define NC 32            // LSEQ / CS

typedef __attribute__((ext_vector_type(8))) short short8;
typedef __attribute__((ext_vector_type(4))) float floatx4;
typedef __attribute__((ext_vector_type(4))) float float4v;
typedef _Float16 h2 __attribute__((ext_vector_type(2)));

#define NEG_BIG (-1.0e30f)
#define C_LOG2E 1.4426950408889634f
#define LOG2_HX0 (-19.931568569324174f)   // log2(1e-6)

__device__ __forceinline__ float exp2_hw(float x) {
#if __has_builtin(__builtin_amdgcn_exp2f)
    return __builtin_amdgcn_exp2f(x);     // v_exp_f32
#else
    return exp2f(x);
#endif
}

__device__ __forceinline__ float log2_hw(float x) {
#if __has_builtin(__builtin_amdgcn_logf)
    return __builtin_amdgcn_logf(x);      // v_log_f32 (base-2)
#else
    return log2f(x);
#endif
}

// log2(2^p + 2^q), robust for -inf-ish inputs
__device__ __forceinline__ float logaddexp2_f(float p, float q) {
    float m = fmaxf(p, q);
    float d = -fabsf(p - q);
    return m + log2_hw(1.0f + exp2_hw(d));
}

__device__ __forceinline__ float bf16u_to_f(unsigned short u) {
    unsigned int w = ((unsigned int)u) << 16;
    float f;
    __builtin_memcpy(&f, &w, 4);
    return f;
}

__device__ __forceinline__ unsigned short f_to_bf16u(float f) {
    __hip_bfloat16 h = __float2bfloat16(f);
    unsigned short u;
    __builtin_memcpy(&u, &h, 2);
    return u;
}

__device__ __forceinline__ void gload_lds16(const void* g, void* l) {
    __builtin_amdgcn_global_load_lds(
        (const __attribute__((address_space(1))) unsigned int*)g,
        (__attribute__((address_space(3))) unsigned int*)l, 16, 0, 0);
}

// ---------------------------------------------------------------------------
// Kernel 0: dtype detect (single block) + bias -> f32. Vectorized loads.
// fp32 data: low u16 halves uniform -> bf16-NaN exponent P=1/256,
// E[hits in 16384] = 64; bf16 N(0,1) data: 0 hits.
// ---------------------------------------------------------------------------
__global__ void detect_and_bias(const unsigned short* __restrict__ xu,
                                const void* __restrict__ bsrc,
                                int* __restrict__ flag,
                                float* __restrict__ bdst) {
    __shared__ int cnt;
    if (threadIdx.x == 0) cnt = 0;
    __syncthreads();
    const short8* x8 = (const short8*)xu;   // 16384 u16 = 2048 short8
    int local = 0;
    #pragma unroll
    for (int j = 0; j < 8; j++) {
        short8 v = x8[threadIdx.x + j * 256];
        #pragma unroll
        for (int e = 0; e < 8; e++) {
            unsigned short u = (unsigned short)v[e];
            if (((u >> 7) & 0xFF) == 0xFF) local++;
        }
    }
    if (local) atomicAdd(&cnt, local);
    __syncthreads();
    int f = (cnt > 8) ? 1 : 0;
    if (threadIdx.x == 0) flag[0] = f;
    #pragma unroll
    for (int j = 0; j < 6; j++) {
        int i = threadIdx.x + j * 256;
        bdst[i] = f ? ((const float*)bsrc)[i]
                    : bf16u_to_f(((const unsigned short*)bsrc)[i]);
    }
}

// ---------------------------------------------------------------------------
// Kernel 0b: normalize x and W to bf16 (role by block range). Vector loads.
//   [0, 8192) -> x (16777216 elems), [8192, 8576) -> W (786432 elems)
// ---------------------------------------------------------------------------
__global__ __launch_bounds__(256)
void convert_inputs(const void* __restrict__ x, const void* __restrict__ W,
                    unsigned short* __restrict__ xc,
                    unsigned short* __restrict__ Wc,
                    const int* __restrict__ flag) {
    const int bx = blockIdx.x;
    const void* src;
    unsigned short* dst;
    int i;
    if (bx < 8192) { src = x; dst = xc; i = (bx * 256 + threadIdx.x) * 8; }
    else           { src = W; dst = Wc; i = ((bx - 8192) * 256 + threadIdx.x) * 8; }
    if (*flag) {
        const float4v* s4 = (const float4v*)((const float*)src + i);
        float4v a = s4[0], b = s4[1];
        short8 v;
        v[0] = (short)f_to_bf16u(a[0]); v[1] = (short)f_to_bf16u(a[1]);
        v[2] = (short)f_to_bf16u(a[2]); v[3] = (short)f_to_bf16u(a[3]);
        v[4] = (short)f_to_bf16u(b[0]); v[5] = (short)f_to_bf16u(b[1]);
        v[6] = (short)f_to_bf16u(b[2]); v[7] = (short)f_to_bf16u(b[3]);
        *(short8*)&dst[i] = v;
    } else {
        *(short8*)&dst[i] = *(const short8*)&((const short*)src)[i];
    }
}

// ---------------------------------------------------------------------------
// Kernel 1: fused GEMM + gates + single-pass scan + output.
// Block 256 = 4 waves (2x2), grid (256, 8): by=blockIdx.x (row block /
// chunk), bx=blockIdx.y (64-col group). global_load_lds staging, LDS XOR
// swizzle. After the K-loop: epilogue -> sc (LDS only); per-wave 32-t
// sub-scan -> sa/sb (LDS); wave 0 publishes chunk aggregate (flag=1);
// ALL waves do parallel segmented lookback over predecessors; combine in
// LDS; each wave folds lower sub-summaries and replays its 32 timesteps,
// writing exp2(r) directly to out.
// ---------------------------------------------------------------------------
__global__ __launch_bounds__(256, 3)
void gemm_gates(const unsigned short* __restrict__ x,
                const unsigned short* __restrict__ W,
                const float* __restrict__ bias,
                float* __restrict__ aggA, float* __restrict__ aggB,
                int* __restrict__ flags,
                void* __restrict__ outv, const int* __restrict__ oflag) {
    __shared__ __align__(16) char ldsbuf[40960];
    short* Alds = (short*)ldsbuf;              // 16 KB during K-loop
    short* Blds = (short*)(ldsbuf + 16384);    // 24 KB during K-loop
    h2* sc = (h2*)ldsbuf;                      // 16 KB after K-loop (128t x 64h)
    float* sa = (float*)(ldsbuf + 32768);      // 1 KB sub-summary A
    float* sb = (float*)(ldsbuf + 33792);      // 1 KB sub-summary B
    float* law = (float*)(ldsbuf + 34816);     // 1 KB segment products A
    float* lbw = (float*)(ldsbuf + 35840);     // 1 KB segment products B

    const int by = blockIdx.x;             // row block 0..255 (XCD = by%8)
    const int bx = blockIdx.y;             // col block 0..7 (64 cols/gate)
    const int tid = threadIdx.x;
    const int lane = tid & 63;
    const int w = tid >> 6;
    const int wr = (w >> 1) * 64;
    const int wc2 = w & 1;
    const int l8 = lane >> 3, s8 = lane & 7;
    const int sg = s8 ^ l8;                // swizzled global seg for staging
    const int fr = lane & 15;
    const int q = lane >> 4;

    const int R0 = by * BM;

    floatx4 acc[4][6];
    #pragma unroll
    for (int i = 0; i < 4; i++)
        #pragma unroll
        for (int j = 0; j < 6; j++)
            acc[i][j] = (floatx4){0.f, 0.f, 0.f, 0.f};

    const short* xg = (const short*)x;
    const short* wg = (const short*)W;

    for (int k0 = 0; k0 < H_DIM; k0 += BK) {
        __syncthreads();
        #pragma unroll
        for (int i = 0; i < 4; i++) {
            int c = w * 4 + i;
            const short* g = xg + (size_t)(R0 + c * 8 + l8) * H_DIM + k0 + sg * 8;
            gload_lds16(g, &Alds[c * 512]);
        }
        #pragma unroll
        for (int i = 0; i < 6; i++) {
            int c = w * 6 + i;
            int br = c * 8 + l8;
            int wrow = (br >> 6) * H_DIM + bx * 64 + (br & 63);
            const short* g = wg + (size_t)wrow * H_DIM + k0 + sg * 8;
            gload_lds16(g, &Blds[c * 512]);
        }
        __syncthreads();

        #pragma unroll
        for (int ks = 0; ks < 2; ks++) {
            const int s = ks * 4 + q;
            short8 af[4], bf[6];
            #pragma unroll
            for (int mt = 0; mt < 4; mt++) {
                int ar = wr + mt * 16 + fr;
                af[mt] = *(const short8*)&Alds[ar * BK + ((s ^ (ar & 7)) << 3)];
            }
            #pragma unroll
            for (int j = 0; j < 6; j++) {
                int nt = (j >> 1) * 4 + wc2 * 2 + (j & 1);
                int brr = nt * 16 + fr;
                bf[j] = *(const short8*)&Blds[brr * BK + ((s ^ (brr & 7)) << 3)];
            }
            #pragma unroll
            for (int mt = 0; mt < 4; mt++)
                #pragma unroll
                for (int j = 0; j < 6; j++)
                    acc[mt][j] = __builtin_amdgcn_mfma_f32_16x16x32_bf16(
                        af[mt], bf[j], acc[mt][j], 0, 0, 0);
        }
    }

    __syncthreads();   // staging LDS dead; reuse as sc

    // Epilogue: C/D layout col=lane&15, row=quad*4+reg [m89/m91].
    // sigma-sum form, all in log2 units. LDS only (no plv).
    const int tloc0 = wr + q * 4;
    #pragma unroll
    for (int jj = 0; jj < 2; jj++) {
        int hl = wc2 * 32 + jj * 16 + fr;
        int hcol = bx * 64 + hl;
        float bfv = bias[hcol];
        float biv = bias[H_DIM + hcol];
        float bhv = bias[2 * H_DIM + hcol];
        float bf2 = -bfv * C_LOG2E;        // fold bias into exp arg via fma
        float bi2 = -biv * C_LOG2E;
        #pragma unroll
        for (int mt = 0; mt < 4; mt++) {
            #pragma unroll
            for (int r = 0; r < 4; r++) {
                float ef = exp2_hw(fminf(fmaf(acc[mt][jj][r], -C_LOG2E, bf2), 126.0f));
                float ei = exp2_hw(fminf(fmaf(acc[mt][2 + jj][r], -C_LOG2E, bi2), 126.0f));
                float hp = acc[mt][4 + jj][r] + bhv;
                float eh = exp2_hw(fminf(-hp * C_LOG2E, 126.0f));
                float afv = 1.0f + ef, aiv = 1.0f + ei;
                float sfi = afv + aiv;
                float ls = log2_hw(sfi);
                float lf = log2_hw(aiv) - ls;                  // log2 f'
                float marg = (hp >= 0.0f) ? (hp + 0.5f) : (1.0f + eh);
                float lm = log2_hw(marg);
                float lg = (hp >= 0.0f) ? lm : -lm;            // log2 g
                float lv = (log2_hw(afv) - ls) + lg;           // log2 (i' g)
                h2 pk;
                pk[0] = (_Float16)lf;
                pk[1] = (_Float16)lv;
                sc[(tloc0 + mt * 16 + r) * 64 + hl] = pk;
            }
        }
    }

    __syncthreads();

    const int c = by & 31;
    const int fidx = by * 8 + bx;
    // Wave w scans t in [w*32, w*32+32) for col=lane -> LDS sub-summary.
    {
        float a = 0.f, bacc = NEG_BIG;
        const int t0 = w * 32;
        #pragma unroll 4
        for (int t = t0; t < t0 + 32; t++) {
            h2 p = sc[t * 64 + lane];
            float f = (float)p[0];
            bacc = logaddexp2_f(f + bacc, (float)p[1]);
            a += f;
        }
        sa[w * 64 + lane] = a;
        sb[w * 64 + lane] = bacc;
    }
    __syncthreads();

    // Wave 0: fold chunk aggregate and publish (flag=1). Meanwhile waves
    // 1-3 have already started their lookback segments below.
    if (w == 0) {
        float Ac = sa[lane], Bc = sb[lane];
        #pragma unroll
        for (int s = 1; s < 4; s++) {
            float as = sa[s * 64 + lane], bs = sb[s * 64 + lane];
            Bc = logaddexp2_f(as + Bc, bs);
            Ac += as;
        }
        aggA[fidx * 64 + lane] = Ac;
        aggB[fidx * 64 + lane] = Bc;
        __threadfence();
        if (lane == 0)
            __hip_atomic_store(&flags[fidx], 1, __ATOMIC_RELEASE,
                               __HIP_MEMORY_SCOPE_AGENT);
    }

    // Parallel segmented lookback: wave w folds predecessors
    // cp in [lo, hi) (contiguous, wave 0 = highest), descending.
    // Empty segments leave the identity (A=0, B=-inf). Aggregates-only:
    // every predecessor's payload is live right after its epilogue.
    float Ap = 0.f, Bp = NEG_BIG;
    {
        const int per = (c + 3) >> 2;
        int hi = c - w * per; if (hi < 0) hi = 0;
        int lo = hi - per;    if (lo < 0) lo = 0;
        for (int cp = hi - 1; cp >= lo; cp--) {
            int f2 = fidx - (c - cp) * 8;       // same bx, lower by
            while (__hip_atomic_load(&flags[f2], __ATOMIC_ACQUIRE,
                                     __HIP_MEMORY_SCOPE_AGENT) == 0)
                __builtin_amdgcn_s_sleep(1);
            float At = aggA[f2 * 64 + lane], Bt = aggB[f2 * 64 + lane];
            Bp = logaddexp2_f(Ap + Bt, Bp);     // P = P ∘ T_cp
            Ap += At;
        }
    }
    law[w * 64 + lane] = Ap;
    lbw[w * 64 + lane] = Bp;
    __syncthreads();

    // Combine 4 segment products (seg 0 = highest cps) and apply to the
    // initial state; then fold sub-summaries below this wave and replay.
    {
        float A = law[lane], B = lbw[lane];
        #pragma unroll
        for (int s2 = 1; s2 < 4; s2++) {
            float As = law[s2 * 64 + lane], Bs = lbw[s2 * 64 + lane];
            B = logaddexp2_f(A + Bs, B);        // P = P ∘ Seg_s2
            A += As;
        }
        float r = logaddexp2_f(A + LOG2_HX0, B);
        #pragma unroll
        for (int s = 0; s < 4; s++) {
            if (s < w)
                r = logaddexp2_f(sa[s * 64 + lane] + r, sb[s * 64 + lane]);
        }

        const int t0 = w * 32;
        const size_t row0 = (size_t)by * BM + t0;     // = n*LSEQ + c*CS + t0
        const int col = bx * 64 + lane;
        if (*oflag) {
            float* of = (float*)outv;
            #pragma unroll 4
            for (int t = 0; t < 32; t++) {
                h2 p = sc[(t0 + t) * 64 + lane];
                r = logaddexp2_f((float)p[0] + r, (float)p[1]);
                of[(row0 + t) * H_DIM + col] = exp2_hw(r);
            }
        } else {
            unsigned short* ob = (unsigned short*)outv;
            #pragma unroll 4
            for (int t = 0; t < 32; t++) {
                h2 p = sc[(t0 + t) * 64 + lane];
                r = logaddexp2_f((float)p[0] + r, (float)p[1]);
                ob[(row0 + t) * H_DIM + col] = f_to_bf16u(exp2_hw(r));
            }
        }
    }
}

extern "C" void kernel_launch(void* const* d_in, const int* in_sizes, int n_in,
                              void* d_out, int out_size, void* d_ws, size_t ws_size,
                              hipStream_t stream) {
    const void* x = d_in[0];
    const void* W = d_in[1];
    const void* b = d_in[2];

    char* wsb = (char*)d_ws;
    int* flag            = (int*)wsb;                          // 16 B
    float* bconv         = (float*)(wsb + 16);                 // 6 KB
    unsigned short* xc   = (unsigned short*)(wsb + 16384);     // 32 MB
    unsigned short* Wc   = (unsigned short*)(wsb + 16384 + 33554432);  // 1.5 MB
    float* aggA          = (float*)(wsb + 36700160);           // 512 KB
    float* aggB          = (float*)(wsb + 36700160 + 524288);  // 512 KB
    int* flags           = (int*)(wsb + 36700160 + 1048576);   // 8 KB

    detect_and_bias<<<1, 256, 0, stream>>>((const unsigned short*)x, b, flag, bconv);
    convert_inputs<<<8576, 256, 0, stream>>>(x, W, xc, Wc, flag);
    hipMemsetAsync(flags, 0, 2048 * sizeof(int), stream);

    dim3 g1(M_TOTAL / BM, H_DIM / 64);   // (256, 8): by on x for XCD share
    gemm_gates<<<g1, 256, 0, stream>>>(xc, Wc, bconv, aggA, aggB,
                                       flags, d_out, flag);
}

// Round 9
// 498.798 us; speedup vs baseline: 1.0972x; 1.0972x over previous
//
#include <hip/hip_runtime.h>
#include <hip/hip_bf16.h>

// minLSTM: pre = x @ W^T + b (M=32768, N=1536, K=512), log-space gates,
// chunked log-space scan over L=4096 per (n,h), out = exp(log_h).
// ALL log-domain values are in LOG2 units (v_exp/v_log are base-2 native).
// Gate math: sigma-sum identity (3 exp + 4 log per position).
// Pipeline: detect(dtype)+bias -> convert x,W to bf16 -> fused GEMM+gates+
// chunk summaries -> sub-chunk replay. GEMM: round-1/5 proven shape
// (bf16 global_load_lds staging, 40KB LDS), grid (256,8) so all 8
// col-blocks of a row-block share one XCD L2 (FETCH 133->58MB).
// NOTE: in_sizes/out_size are ELEMENT counts (harness slices flat[off:off+sz])
// -- dtype is NOT host-derivable; the device-side detect kernel is required
// (round-8 host-size detection failed, absmax 5.7).
// FALSIFIED (do not revisit):
//  - rounds 2-4: any fp32-A-in-GEMM staging loses more than 2-pass convert.
//  - rounds 6-7: fused single-pass scan via decoupled lookback; cross-XCD
//    flag spinning collapses memory BW (377us serial, 450us parallel).
//  - round 9 analysis: scan_apply is BW-bound (serial chain ~0.5us/block vs
//    ~22us BW floor) -- finer sub-summaries / prefix-plv buy nothing, and
//    fp16 prefix transforms fail the absmax precision budget.

#define H_DIM 512
#define LSEQ 4096
#define NBATCH 8
#define M_TOTAL (NBATCH * LSEQ)  // 32768

#define BM 128
#define BK 64

#define CS 128
#define NC 32            // LSEQ / CS

typedef __attribute__((ext_vector_type(8))) short short8;
typedef __attribute__((ext_vector_type(4))) float floatx4;
typedef __attribute__((ext_vector_type(4))) float float4v;
typedef _Float16 h2 __attribute__((ext_vector_type(2)));
typedef _Float16 h8 __attribute__((ext_vector_type(8)));
typedef __attribute__((ext_vector_type(2))) unsigned int uint2v;

#define NEG_BIG (-1.0e30f)
#define C_LOG2E 1.4426950408889634f
#define LOG2_HX0 (-19.931568569324174f)   // log2(1e-6)

__device__ __forceinline__ float exp2_hw(float x) {
#if __has_builtin(__builtin_amdgcn_exp2f)
    return __builtin_amdgcn_exp2f(x);     // v_exp_f32
#else
    return exp2f(x);
#endif
}

__device__ __forceinline__ float log2_hw(float x) {
#if __has_builtin(__builtin_amdgcn_logf)
    return __builtin_amdgcn_logf(x);      // v_log_f32 (base-2)
#else
    return log2f(x);
#endif
}

// log2(2^p + 2^q), robust for -inf-ish inputs
__device__ __forceinline__ float logaddexp2_f(float p, float q) {
    float m = fmaxf(p, q);
    float d = -fabsf(p - q);
    return m + log2_hw(1.0f + exp2_hw(d));
}

__device__ __forceinline__ float bf16u_to_f(unsigned short u) {
    unsigned int w = ((unsigned int)u) << 16;
    float f;
    __builtin_memcpy(&f, &w, 4);
    return f;
}

__device__ __forceinline__ unsigned short f_to_bf16u(float f) {
    __hip_bfloat16 h = __float2bfloat16(f);
    unsigned short u;
    __builtin_memcpy(&u, &h, 2);
    return u;
}

__device__ __forceinline__ void gload_lds16(const void* g, void* l) {
    __builtin_amdgcn_global_load_lds(
        (const __attribute__((address_space(1))) unsigned int*)g,
        (__attribute__((address_space(3))) unsigned int*)l, 16, 0, 0);
}

// ---------------------------------------------------------------------------
// Kernel 0: dtype detect (single block) + bias -> f32. Vectorized loads.
// fp32 data: low u16 halves uniform -> bf16-NaN exponent P=1/256,
// E[hits in 16384] = 64; bf16 N(0,1) data: 0 hits.
// ---------------------------------------------------------------------------
__global__ void detect_and_bias(const unsigned short* __restrict__ xu,
                                const void* __restrict__ bsrc,
                                int* __restrict__ flag,
                                float* __restrict__ bdst) {
    __shared__ int cnt;
    if (threadIdx.x == 0) cnt = 0;
    __syncthreads();
    const short8* x8 = (const short8*)xu;   // 16384 u16 = 2048 short8
    int local = 0;
    #pragma unroll
    for (int j = 0; j < 8; j++) {
        short8 v = x8[threadIdx.x + j * 256];
        #pragma unroll
        for (int e = 0; e < 8; e++) {
            unsigned short u = (unsigned short)v[e];
            if (((u >> 7) & 0xFF) == 0xFF) local++;
        }
    }
    if (local) atomicAdd(&cnt, local);
    __syncthreads();
    int f = (cnt > 8) ? 1 : 0;
    if (threadIdx.x == 0) flag[0] = f;
    #pragma unroll
    for (int j = 0; j < 6; j++) {
        int i = threadIdx.x + j * 256;
        bdst[i] = f ? ((const float*)bsrc)[i]
                    : bf16u_to_f(((const unsigned short*)bsrc)[i]);
    }
}

// ---------------------------------------------------------------------------
// Kernel 0b: normalize x and W to bf16 (role by block range). Vector loads.
//   [0, 8192) -> x (16777216 elems), [8192, 8576) -> W (786432 elems)
// x-range blocks are REMAPPED for XCD affinity: data block bx covers xc
// rows 4bx..4bx+3, consumed by gemm row-group g=bx>>5 on XCD g%8. Launch
// id l runs on XCD l%8; bijection l->bx ensures g%8 == l%8 so converted
// lines sit in the consuming XCD's L2.
// ---------------------------------------------------------------------------
__global__ __launch_bounds__(256)
void convert_inputs(const void* __restrict__ x, const void* __restrict__ W,
                    unsigned short* __restrict__ xc,
                    unsigned short* __restrict__ Wc,
                    const int* __restrict__ flag) {
    const int bid = blockIdx.x;
    const void* src;
    unsigned short* dst;
    int i;
    if (bid < 8192) {
        int b = bid & 7, m = bid >> 3;
        int a = m >> 5, j = m & 31;
        int bx = (((a << 3) + b) << 5) + j;   // row-group 8a+b ≡ bid (mod 8)
        src = x; dst = xc; i = (bx * 256 + threadIdx.x) * 8;
    } else {
        src = W; dst = Wc; i = ((bid - 8192) * 256 + threadIdx.x) * 8;
    }
    if (*flag) {
        const float4v* s4 = (const float4v*)((const float*)src + i);
        float4v a = s4[0], b = s4[1];
        short8 v;
        v[0] = (short)f_to_bf16u(a[0]); v[1] = (short)f_to_bf16u(a[1]);
        v[2] = (short)f_to_bf16u(a[2]); v[3] = (short)f_to_bf16u(a[3]);
        v[4] = (short)f_to_bf16u(b[0]); v[5] = (short)f_to_bf16u(b[1]);
        v[6] = (short)f_to_bf16u(b[2]); v[7] = (short)f_to_bf16u(b[3]);
        *(short8*)&dst[i] = v;
    } else {
        *(short8*)&dst[i] = *(const short8*)&((const short*)src)[i];
    }
}

// ---------------------------------------------------------------------------
// Kernel 1: GEMM + gate math + fused scan summaries (round-5 proven shape).
// Block 256 = 4 waves (2x2). global_load_lds width-16 staging, bf16 inputs.
// LDS XOR swizzle (verified: conflicts ~0). Tail: wave w scans its 32-t
// sub-segment -> Asub/Bsub (global) + LDS; wave 0 folds 4 -> Asum/Bval.
// Grid (256, 8): by = blockIdx.x so same-by col-blocks share an XCD L2.
// launch_bounds (256,4): 40960B LDS x4 = 160KiB pool exactly; VGPR 84 <=
// 128 budget at 16 waves/CU -> 4th resident block to hide the barrier
// drain (round-5 occupancy was only 27%).
// ---------------------------------------------------------------------------
__global__ __launch_bounds__(256, 4)
void gemm_gates(const unsigned short* __restrict__ x,
                const unsigned short* __restrict__ W,
                const float* __restrict__ bias,
                h2* __restrict__ plv,
                float* __restrict__ Asum, float* __restrict__ Bval,
                float* __restrict__ Asub, float* __restrict__ Bsub) {
    __shared__ __align__(16) char ldsbuf[40960];
    short* Alds = (short*)ldsbuf;              // 16 KB during K-loop
    short* Blds = (short*)(ldsbuf + 16384);    // 24 KB during K-loop
    h2* sc = (h2*)ldsbuf;                      // 32 KB after K-loop
    float* sa = (float*)(ldsbuf + 32768);      // 1 KB sub-summary A
    float* sb = sa + 256;                      // 1 KB sub-summary B

    const int by = blockIdx.x;             // row block 0..255 (XCD = by%8)
    const int bx = blockIdx.y;             // col block 0..7 (64 cols/gate)
    const int tid = threadIdx.x;
    const int lane = tid & 63;
    const int w = tid >> 6;
    const int wr = (w >> 1) * 64;
    const int wc2 = w & 1;
    const int l8 = lane >> 3, s8 = lane & 7;
    const int sg = s8 ^ l8;                // swizzled global seg for staging
    const int fr = lane & 15;
    const int q = lane >> 4;

    const int R0 = by * BM;

    floatx4 acc[4][6];
    #pragma unroll
    for (int i = 0; i < 4; i++)
        #pragma unroll
        for (int j = 0; j < 6; j++)
            acc[i][j] = (floatx4){0.f, 0.f, 0.f, 0.f};

    const short* xg = (const short*)x;
    const short* wg = (const short*)W;

    for (int k0 = 0; k0 < H_DIM; k0 += BK) {
        __syncthreads();
        #pragma unroll
        for (int i = 0; i < 4; i++) {
            int c = w * 4 + i;
            const short* g = xg + (size_t)(R0 + c * 8 + l8) * H_DIM + k0 + sg * 8;
            gload_lds16(g, &Alds[c * 512]);
        }
        #pragma unroll
        for (int i = 0; i < 6; i++) {
            int c = w * 6 + i;
            int br = c * 8 + l8;
            int wrow = (br >> 6) * H_DIM + bx * 64 + (br & 63);
            const short* g = wg + (size_t)wrow * H_DIM + k0 + sg * 8;
            gload_lds16(g, &Blds[c * 512]);
        }
        __syncthreads();

        #pragma unroll
        for (int ks = 0; ks < 2; ks++) {
            const int s = ks * 4 + q;
            short8 af[4], bf[6];
            #pragma unroll
            for (int mt = 0; mt < 4; mt++) {
                int ar = wr + mt * 16 + fr;
                af[mt] = *(const short8*)&Alds[ar * BK + ((s ^ (ar & 7)) << 3)];
            }
            #pragma unroll
            for (int j = 0; j < 6; j++) {
                int nt = (j >> 1) * 4 + wc2 * 2 + (j & 1);
                int brr = nt * 16 + fr;
                bf[j] = *(const short8*)&Blds[brr * BK + ((s ^ (brr & 7)) << 3)];
            }
            #pragma unroll
            for (int mt = 0; mt < 4; mt++)
                #pragma unroll
                for (int j = 0; j < 6; j++)
                    acc[mt][j] = __builtin_amdgcn_mfma_f32_16x16x32_bf16(
                        af[mt], bf[j], acc[mt][j], 0, 0, 0);
        }
    }

    __syncthreads();   // staging LDS dead; reuse as sc

    // Epilogue: C/D layout col=lane&15, row=quad*4+reg [m89/m91].
    // sigma-sum form, all in log2 units:
    //   af=1+2^(-f*log2e), ai=1+2^(-i*log2e), s=af+ai
    //   lf = log2(ai)-log2(s); lv = log2(af)-log2(s) + lg
    //   lg = h>=0 ? log2(h+0.5) : -log2(1+2^(-h*log2e))  (argument-select)
    const int rowb = R0 + wr + q * 4;
    const int tloc0 = wr + q * 4;
    #pragma unroll
    for (int jj = 0; jj < 2; jj++) {
        int hl = wc2 * 32 + jj * 16 + fr;
        int hcol = bx * 64 + hl;
        float bfv = bias[hcol];
        float biv = bias[H_DIM + hcol];
        float bhv = bias[2 * H_DIM + hcol];
        float bf2 = -bfv * C_LOG2E;        // fold bias into exp arg via fma
        float bi2 = -biv * C_LOG2E;
        #pragma unroll
        for (int mt = 0; mt < 4; mt++) {
            #pragma unroll
            for (int r = 0; r < 4; r++) {
                float ef = exp2_hw(fminf(fmaf(acc[mt][jj][r], -C_LOG2E, bf2), 126.0f));
                float ei = exp2_hw(fminf(fmaf(acc[mt][2 + jj][r], -C_LOG2E, bi2), 126.0f));
                float hp = acc[mt][4 + jj][r] + bhv;
                float eh = exp2_hw(fminf(-hp * C_LOG2E, 126.0f));
                float afv = 1.0f + ef, aiv = 1.0f + ei;
                float sfi = afv + aiv;
                float ls = log2_hw(sfi);
                float lf = log2_hw(aiv) - ls;                  // log2 f'
                float marg = (hp >= 0.0f) ? (hp + 0.5f) : (1.0f + eh);
                float lm = log2_hw(marg);
                float lg = (hp >= 0.0f) ? lm : -lm;            // log2 g
                float lv = (log2_hw(afv) - ls) + lg;           // log2 (i' g)
                int row = rowb + mt * 16 + r;
                h2 pk;
                pk[0] = (_Float16)lf;
                pk[1] = (_Float16)lv;
                plv[(size_t)row * H_DIM + hcol] = pk;
                sc[(tloc0 + mt * 16 + r) * 64 + hl] = pk;
            }
        }
    }

    __syncthreads();

    const int n = by >> 5, c = by & 31;
    // Wave w scans t in [w*32, w*32+32) for col=lane; publish sub-summary.
    {
        float a = 0.f, bacc = NEG_BIG;
        const int t0 = w * 32;
        #pragma unroll 4
        for (int t = t0; t < t0 + 32; t++) {
            h2 p = sc[t * 64 + lane];
            float f = (float)p[0];
            bacc = logaddexp2_f(f + bacc, (float)p[1]);
            a += f;
        }
        sa[w * 64 + lane] = a;
        sb[w * 64 + lane] = bacc;
        size_t o = (((size_t)n * NC + c) * 4 + w) * H_DIM + bx * 64 + lane;
        Asub[o] = a;
        Bsub[o] = bacc;
    }
    __syncthreads();

    if (w == 0) {
        float a = sa[lane], b = sb[lane];
        #pragma unroll
        for (int s = 1; s < 4; s++) {
            float as = sa[s * 64 + lane], bs = sb[s * 64 + lane];
            b = logaddexp2_f(as + b, bs);
            a += as;
        }
        size_t o = ((size_t)n * NC + c) * H_DIM + bx * 64 + lane;
        Asum[o] = a;
        Bval[o] = b;
    }
}

// ---------------------------------------------------------------------------
// Kernel 2: sub-chunk replay. Grid (64, 8), 256 threads.
// Block cc: c = cc&31 (low bits -> XCD c%8, SAME XCD whose gemm blocks
// wrote chunk c's plv rows/summaries: gemm linear%8 = by%8 = c%8).
// spair = cc>>5; thread t: s = spair*2 + (t>>7), 4 h-cols = (t&127)*4.
// 4 independent logaddexp2 chains/thread, 16B loads+stores. Carry =
// c chunk folds (4-wide batched) + s sub folds, then 32-t replay.
// BW-bound (~22us floor); serial chain is ~0.5us/block -- don't restructure.
// ---------------------------------------------------------------------------
__global__ __launch_bounds__(256)
void scan_apply(const h2* __restrict__ plv,
                const float* __restrict__ Asum, const float* __restrict__ Bval,
                const float* __restrict__ Asub, const float* __restrict__ Bsub,
                void* __restrict__ outv, const int* __restrict__ flag) {
    const int cc = blockIdx.x;          // 0..63
    const int n = blockIdx.y;
    const int c = cc & 31;
    const int s = (cc >> 5) * 2 + (threadIdx.x >> 7);   // wave-uniform
    const int h0 = (threadIdx.x & 127) * 4;
    const int f32out = *flag;

    float r0 = LOG2_HX0, r1 = r0, r2 = r0, r3 = r0;   // log2(1e-6)
    size_t so = (size_t)n * NC * H_DIM + h0;
    int cp = 0;
    for (; cp + 4 <= c; cp += 4) {
        float4v A0 = *(const float4v*)&Asum[so + (size_t)(cp + 0) * H_DIM];
        float4v B0 = *(const float4v*)&Bval[so + (size_t)(cp + 0) * H_DIM];
        float4v A1 = *(const float4v*)&Asum[so + (size_t)(cp + 1) * H_DIM];
        float4v B1 = *(const float4v*)&Bval[so + (size_t)(cp + 1) * H_DIM];
        float4v A2 = *(const float4v*)&Asum[so + (size_t)(cp + 2) * H_DIM];
        float4v B2 = *(const float4v*)&Bval[so + (size_t)(cp + 2) * H_DIM];
        float4v A3 = *(const float4v*)&Asum[so + (size_t)(cp + 3) * H_DIM];
        float4v B3 = *(const float4v*)&Bval[so + (size_t)(cp + 3) * H_DIM];
        r0 = logaddexp2_f(A0[0] + r0, B0[0]); r1 = logaddexp2_f(A0[1] + r1, B0[1]);
        r2 = logaddexp2_f(A0[2] + r2, B0[2]); r3 = logaddexp2_f(A0[3] + r3, B0[3]);
        r0 = logaddexp2_f(A1[0] + r0, B1[0]); r1 = logaddexp2_f(A1[1] + r1, B1[1]);
        r2 = logaddexp2_f(A1[2] + r2, B1[2]); r3 = logaddexp2_f(A1[3] + r3, B1[3]);
        r0 = logaddexp2_f(A2[0] + r0, B2[0]); r1 = logaddexp2_f(A2[1] + r1, B2[1]);
        r2 = logaddexp2_f(A2[2] + r2, B2[2]); r3 = logaddexp2_f(A2[3] + r3, B2[3]);
        r0 = logaddexp2_f(A3[0] + r0, B3[0]); r1 = logaddexp2_f(A3[1] + r1, B3[1]);
        r2 = logaddexp2_f(A3[2] + r2, B3[2]); r3 = logaddexp2_f(A3[3] + r3, B3[3]);
    }
    for (; cp < c; cp++) {
        float4v A = *(const float4v*)&Asum[so + (size_t)cp * H_DIM];
        float4v B = *(const float4v*)&Bval[so + (size_t)cp * H_DIM];
        r0 = logaddexp2_f(A[0] + r0, B[0]); r1 = logaddexp2_f(A[1] + r1, B[1]);
        r2 = logaddexp2_f(A[2] + r2, B[2]); r3 = logaddexp2_f(A[3] + r3, B[3]);
    }
    size_t sub = (((size_t)n * NC + c) * 4) * H_DIM + h0;
    for (int sp = 0; sp < s; sp++) {
        float4v A = *(const float4v*)&Asub[sub + (size_t)sp * H_DIM];
        float4v B = *(const float4v*)&Bsub[sub + (size_t)sp * H_DIM];
        r0 = logaddexp2_f(A[0] + r0, B[0]); r1 = logaddexp2_f(A[1] + r1, B[1]);
        r2 = logaddexp2_f(A[2] + r2, B[2]); r3 = logaddexp2_f(A[3] + r3, B[3]);
    }

    size_t base = ((size_t)n * LSEQ + (size_t)c * CS + s * 32) * H_DIM + h0;
    if (f32out) {
        float* of = (float*)outv;
        #pragma unroll 4
        for (int t = 0; t < 32; t++) {
            size_t idx = base + (size_t)t * H_DIM;
            h8 p = *(const h8*)&plv[idx];     // (lf0,lv0,lf1,lv1,lf2,lv2,lf3,lv3)
            r0 = logaddexp2_f((float)p[0] + r0, (float)p[1]);
            r1 = logaddexp2_f((float)p[2] + r1, (float)p[3]);
            r2 = logaddexp2_f((float)p[4] + r2, (float)p[5]);
            r3 = logaddexp2_f((float)p[6] + r3, (float)p[7]);
            float4v o4 = {exp2_hw(r0), exp2_hw(r1), exp2_hw(r2), exp2_hw(r3)};
            *(float4v*)&of[idx] = o4;
        }
    } else {
        unsigned int* ob32 = (unsigned int*)outv;
        #pragma unroll 4
        for (int t = 0; t < 32; t++) {
            size_t idx = base + (size_t)t * H_DIM;
            h8 p = *(const h8*)&plv[idx];
            r0 = logaddexp2_f((float)p[0] + r0, (float)p[1]);
            r1 = logaddexp2_f((float)p[2] + r1, (float)p[3]);
            r2 = logaddexp2_f((float)p[4] + r2, (float)p[5]);
            r3 = logaddexp2_f((float)p[6] + r3, (float)p[7]);
            uint2v pk;
            pk[0] = ((unsigned int)f_to_bf16u(exp2_hw(r1)) << 16) | f_to_bf16u(exp2_hw(r0));
            pk[1] = ((unsigned int)f_to_bf16u(exp2_hw(r3)) << 16) | f_to_bf16u(exp2_hw(r2));
            *(uint2v*)&ob32[idx >> 1] = pk;
        }
    }
}

extern "C" void kernel_launch(void* const* d_in, const int* in_sizes, int n_in,
                              void* d_out, int out_size, void* d_ws, size_t ws_size,
                              hipStream_t stream) {
    const void* x = d_in[0];
    const void* W = d_in[1];
    const void* b = d_in[2];

    char* wsb = (char*)d_ws;
    int* flag            = (int*)wsb;                          // 16 B
    float* bconv         = (float*)(wsb + 16);                 // 6 KB
    unsigned short* xc   = (unsigned short*)(wsb + 16384);     // 32 MB
    unsigned short* Wc   = (unsigned short*)(wsb + 16384 + 33554432);  // 1.5 MB
    h2* plv              = (h2*)(wsb + 36700160);              // 64 MB packed (lf,lv)
    float* Asum          = (float*)(wsb + 103809024);          // 512 KB
    float* Bval          = (float*)(wsb + 104333312);          // 512 KB
    float* Asub          = (float*)(wsb + 104857600);          // 2 MB
    float* Bsub          = (float*)(wsb + 106954752);          // 2 MB

    detect_and_bias<<<1, 256, 0, stream>>>((const unsigned short*)x, b, flag, bconv);
    convert_inputs<<<8576, 256, 0, stream>>>(x, W, xc, Wc, flag);

    dim3 g1(M_TOTAL / BM, H_DIM / 64);   // (256, 8): by on x for XCD share
    gemm_gates<<<g1, 256, 0, stream>>>(xc, Wc, bconv, plv, Asum, Bval, Asub, Bsub);

    dim3 g2(NC * 2, NBATCH);             // (64, 8): c in low bits for XCD match
    scan_apply<<<g2, 256, 0, stream>>>(plv, Asum, Bval, Asub, Bsub, d_out, flag);
}

// Round 10
// 215.041 us; speedup vs baseline: 2.5450x; 2.3196x over previous
//
#include <hip/hip_runtime.h>
#include <hip/hip_bf16.h>

// minLSTM: pre = x @ W^T + b (M=32768, N=1536, K=512), log-space gates,
// chunked log-space scan over L=4096 per (n,h), out = exp(log_h).
// ALL log-domain values are in LOG2 units (v_exp/v_log are base-2 native).
// Gate math: sigma-sum identity (3 exp + 4 log per position).
// Pipeline: detect(dtype)+bias -> convert x,W to bf16 -> fused GEMM+gates+
// chunk summaries -> sub-chunk replay. GEMM: round-1/5 proven shape
// (bf16 global_load_lds staging, 40KB LDS, 3 blocks/CU), grid (256,8) so
// all 8 col-blocks of a row-block share one XCD L2 (FETCH 133->58MB).
// NOTE: in_sizes/out_size are ELEMENT counts -- dtype is NOT host-derivable;
// the device-side detect kernel is required (round-8 failure).
// FALSIFIED (do not revisit):
//  - rounds 2-4: any fp32-A-in-GEMM staging loses more than 2-pass convert.
//  - rounds 6-7: fused single-pass scan via decoupled lookback; cross-XCD
//    flag spinning collapses memory BW (377us serial, 450us parallel).
//  - round 9: __launch_bounds__(256,4) clamps VGPR to 64 < 96 acc regs ->
//    accumulator spill (870MB WRITE, 345us). (256,3)/84VGPR is the optimum;
//    NEVER raise the occupancy bound on this kernel.
//  - scan_apply is BW-bound (~22us floor; serial chain ~0.5us/block) --
//    restructuring buys nothing; fp16 prefix-plv fails precision budget.

#define H_DIM 512
#define LSEQ 4096
#define NBATCH 8
#define M_TOTAL (NBATCH * LSEQ)  // 32768

#define BM 128
#define BK 64

#define CS 128
#define NC 32            // LSEQ / CS

typedef __attribute__((ext_vector_type(8))) short short8;
typedef __attribute__((ext_vector_type(4))) float floatx4;
typedef __attribute__((ext_vector_type(4))) float float4v;
typedef _Float16 h2 __attribute__((ext_vector_type(2)));
typedef _Float16 h8 __attribute__((ext_vector_type(8)));
typedef __attribute__((ext_vector_type(2))) unsigned int uint2v;

#define NEG_BIG (-1.0e30f)
#define C_LOG2E 1.4426950408889634f
#define LOG2_HX0 (-19.931568569324174f)   // log2(1e-6)

__device__ __forceinline__ float exp2_hw(float x) {
#if __has_builtin(__builtin_amdgcn_exp2f)
    return __builtin_amdgcn_exp2f(x);     // v_exp_f32
#else
    return exp2f(x);
#endif
}

__device__ __forceinline__ float log2_hw(float x) {
#if __has_builtin(__builtin_amdgcn_logf)
    return __builtin_amdgcn_logf(x);      // v_log_f32 (base-2)
#else
    return log2f(x);
#endif
}

// log2(2^p + 2^q), robust for -inf-ish inputs
__device__ __forceinline__ float logaddexp2_f(float p, float q) {
    float m = fmaxf(p, q);
    float d = -fabsf(p - q);
    return m + log2_hw(1.0f + exp2_hw(d));
}

__device__ __forceinline__ float bf16u_to_f(unsigned short u) {
    unsigned int w = ((unsigned int)u) << 16;
    float f;
    __builtin_memcpy(&f, &w, 4);
    return f;
}

__device__ __forceinline__ unsigned short f_to_bf16u(float f) {
    __hip_bfloat16 h = __float2bfloat16(f);
    unsigned short u;
    __builtin_memcpy(&u, &h, 2);
    return u;
}

__device__ __forceinline__ void gload_lds16(const void* g, void* l) {
    __builtin_amdgcn_global_load_lds(
        (const __attribute__((address_space(1))) unsigned int*)g,
        (__attribute__((address_space(3))) unsigned int*)l, 16, 0, 0);
}

// ---------------------------------------------------------------------------
// Kernel 0: dtype detect (single block) + bias -> f32. Vectorized loads.
// fp32 data: low u16 halves uniform -> bf16-NaN exponent P=1/256,
// E[hits in 16384] = 64; bf16 N(0,1) data: 0 hits.
// ---------------------------------------------------------------------------
__global__ void detect_and_bias(const unsigned short* __restrict__ xu,
                                const void* __restrict__ bsrc,
                                int* __restrict__ flag,
                                float* __restrict__ bdst) {
    __shared__ int cnt;
    if (threadIdx.x == 0) cnt = 0;
    __syncthreads();
    const short8* x8 = (const short8*)xu;   // 16384 u16 = 2048 short8
    int local = 0;
    #pragma unroll
    for (int j = 0; j < 8; j++) {
        short8 v = x8[threadIdx.x + j * 256];
        #pragma unroll
        for (int e = 0; e < 8; e++) {
            unsigned short u = (unsigned short)v[e];
            if (((u >> 7) & 0xFF) == 0xFF) local++;
        }
    }
    if (local) atomicAdd(&cnt, local);
    __syncthreads();
    int f = (cnt > 8) ? 1 : 0;
    if (threadIdx.x == 0) flag[0] = f;
    #pragma unroll
    for (int j = 0; j < 6; j++) {
        int i = threadIdx.x + j * 256;
        bdst[i] = f ? ((const float*)bsrc)[i]
                    : bf16u_to_f(((const unsigned short*)bsrc)[i]);
    }
}

// ---------------------------------------------------------------------------
// Kernel 0b: normalize x and W to bf16 (role by block range). Vector loads.
//   [0, 8192) -> x (16777216 elems), [8192, 8576) -> W (786432 elems)
// x-range blocks are REMAPPED for XCD affinity: data block bx covers xc
// rows 4bx..4bx+3, consumed by gemm row-group g=bx>>5 on XCD g%8. Launch
// id l runs on XCD l%8; bijection l->bx ensures g%8 == l%8 so converted
// lines land in the consuming XCD's L2.
// ---------------------------------------------------------------------------
__global__ __launch_bounds__(256)
void convert_inputs(const void* __restrict__ x, const void* __restrict__ W,
                    unsigned short* __restrict__ xc,
                    unsigned short* __restrict__ Wc,
                    const int* __restrict__ flag) {
    const int bid = blockIdx.x;
    const void* src;
    unsigned short* dst;
    int i;
    if (bid < 8192) {
        int b = bid & 7, m = bid >> 3;
        int a = m >> 5, j = m & 31;
        int bx = (((a << 3) + b) << 5) + j;   // row-group 8a+b ≡ bid (mod 8)
        src = x; dst = xc; i = (bx * 256 + threadIdx.x) * 8;
    } else {
        src = W; dst = Wc; i = ((bid - 8192) * 256 + threadIdx.x) * 8;
    }
    if (*flag) {
        const float4v* s4 = (const float4v*)((const float*)src + i);
        float4v a = s4[0], b = s4[1];
        short8 v;
        v[0] = (short)f_to_bf16u(a[0]); v[1] = (short)f_to_bf16u(a[1]);
        v[2] = (short)f_to_bf16u(a[2]); v[3] = (short)f_to_bf16u(a[3]);
        v[4] = (short)f_to_bf16u(b[0]); v[5] = (short)f_to_bf16u(b[1]);
        v[6] = (short)f_to_bf16u(b[2]); v[7] = (short)f_to_bf16u(b[3]);
        *(short8*)&dst[i] = v;
    } else {
        *(short8*)&dst[i] = *(const short8*)&((const short*)src)[i];
    }
}

// ---------------------------------------------------------------------------
// Kernel 1: GEMM + gate math + fused scan summaries (round-5 proven shape).
// Block 256 = 4 waves (2x2). global_load_lds width-16 staging, bf16 inputs.
// LDS XOR swizzle (verified: conflicts ~0). Tail: wave w scans its 32-t
// sub-segment -> Asub/Bsub (global) + LDS; wave 0 folds 4 -> Asum/Bval.
// Grid (256, 8): by = blockIdx.x so same-by col-blocks share an XCD L2.
// launch_bounds (256,3): 84 VGPR, 3 blocks/CU. DO NOT RAISE (round-9 spill).
// ---------------------------------------------------------------------------
__global__ __launch_bounds__(256, 3)
void gemm_gates(const unsigned short* __restrict__ x,
                const unsigned short* __restrict__ W,
                const float* __restrict__ bias,
                h2* __restrict__ plv,
                float* __restrict__ Asum, float* __restrict__ Bval,
                float* __restrict__ Asub, float* __restrict__ Bsub) {
    __shared__ __align__(16) char ldsbuf[40960];
    short* Alds = (short*)ldsbuf;              // 16 KB during K-loop
    short* Blds = (short*)(ldsbuf + 16384);    // 24 KB during K-loop
    h2* sc = (h2*)ldsbuf;                      // 32 KB after K-loop
    float* sa = (float*)(ldsbuf + 32768);      // 1 KB sub-summary A
    float* sb = sa + 256;                      // 1 KB sub-summary B

    const int by = blockIdx.x;             // row block 0..255 (XCD = by%8)
    const int bx = blockIdx.y;             // col block 0..7 (64 cols/gate)
    const int tid = threadIdx.x;
    const int lane = tid & 63;
    const int w = tid >> 6;
    const int wr = (w >> 1) * 64;
    const int wc2 = w & 1;
    const int l8 = lane >> 3, s8 = lane & 7;
    const int sg = s8 ^ l8;                // swizzled global seg for staging
    const int fr = lane & 15;
    const int q = lane >> 4;

    const int R0 = by * BM;

    floatx4 acc[4][6];
    #pragma unroll
    for (int i = 0; i < 4; i++)
        #pragma unroll
        for (int j = 0; j < 6; j++)
            acc[i][j] = (floatx4){0.f, 0.f, 0.f, 0.f};

    const short* xg = (const short*)x;
    const short* wg = (const short*)W;

    for (int k0 = 0; k0 < H_DIM; k0 += BK) {
        __syncthreads();
        #pragma unroll
        for (int i = 0; i < 4; i++) {
            int c = w * 4 + i;
            const short* g = xg + (size_t)(R0 + c * 8 + l8) * H_DIM + k0 + sg * 8;
            gload_lds16(g, &Alds[c * 512]);
        }
        #pragma unroll
        for (int i = 0; i < 6; i++) {
            int c = w * 6 + i;
            int br = c * 8 + l8;
            int wrow = (br >> 6) * H_DIM + bx * 64 + (br & 63);
            const short* g = wg + (size_t)wrow * H_DIM + k0 + sg * 8;
            gload_lds16(g, &Blds[c * 512]);
        }
        __syncthreads();

        #pragma unroll
        for (int ks = 0; ks < 2; ks++) {
            const int s = ks * 4 + q;
            short8 af[4], bf[6];
            #pragma unroll
            for (int mt = 0; mt < 4; mt++) {
                int ar = wr + mt * 16 + fr;
                af[mt] = *(const short8*)&Alds[ar * BK + ((s ^ (ar & 7)) << 3)];
            }
            #pragma unroll
            for (int j = 0; j < 6; j++) {
                int nt = (j >> 1) * 4 + wc2 * 2 + (j & 1);
                int brr = nt * 16 + fr;
                bf[j] = *(const short8*)&Blds[brr * BK + ((s ^ (brr & 7)) << 3)];
            }
            #pragma unroll
            for (int mt = 0; mt < 4; mt++)
                #pragma unroll
                for (int j = 0; j < 6; j++)
                    acc[mt][j] = __builtin_amdgcn_mfma_f32_16x16x32_bf16(
                        af[mt], bf[j], acc[mt][j], 0, 0, 0);
        }
    }

    __syncthreads();   // staging LDS dead; reuse as sc

    // Epilogue: C/D layout col=lane&15, row=quad*4+reg [m89/m91].
    // sigma-sum form, all in log2 units:
    //   af=1+2^(-f*log2e), ai=1+2^(-i*log2e), s=af+ai
    //   lf = log2(ai)-log2(s); lv = log2(af)-log2(s) + lg
    //   lg = h>=0 ? log2(h+0.5) : -log2(1+2^(-h*log2e))  (argument-select)
    const int rowb = R0 + wr + q * 4;
    const int tloc0 = wr + q * 4;
    #pragma unroll
    for (int jj = 0; jj < 2; jj++) {
        int hl = wc2 * 32 + jj * 16 + fr;
        int hcol = bx * 64 + hl;
        float bfv = bias[hcol];
        float biv = bias[H_DIM + hcol];
        float bhv = bias[2 * H_DIM + hcol];
        float bf2 = -bfv * C_LOG2E;        // fold bias into exp arg via fma
        float bi2 = -biv * C_LOG2E;
        #pragma unroll
        for (int mt = 0; mt < 4; mt++) {
            #pragma unroll
            for (int r = 0; r < 4; r++) {
                float ef = exp2_hw(fminf(fmaf(acc[mt][jj][r], -C_LOG2E, bf2), 126.0f));
                float ei = exp2_hw(fminf(fmaf(acc[mt][2 + jj][r], -C_LOG2E, bi2), 126.0f));
                float hp = acc[mt][4 + jj][r] + bhv;
                float eh = exp2_hw(fminf(-hp * C_LOG2E, 126.0f));
                float afv = 1.0f + ef, aiv = 1.0f + ei;
                float sfi = afv + aiv;
                float ls = log2_hw(sfi);
                float lf = log2_hw(aiv) - ls;                  // log2 f'
                float marg = (hp >= 0.0f) ? (hp + 0.5f) : (1.0f + eh);
                float lm = log2_hw(marg);
                float lg = (hp >= 0.0f) ? lm : -lm;            // log2 g
                float lv = (log2_hw(afv) - ls) + lg;           // log2 (i' g)
                int row = rowb + mt * 16 + r;
                h2 pk;
                pk[0] = (_Float16)lf;
                pk[1] = (_Float16)lv;
                plv[(size_t)row * H_DIM + hcol] = pk;
                sc[(tloc0 + mt * 16 + r) * 64 + hl] = pk;
            }
        }
    }

    __syncthreads();

    const int n = by >> 5, c = by & 31;
    // Wave w scans t in [w*32, w*32+32) for col=lane; publish sub-summary.
    {
        float a = 0.f, bacc = NEG_BIG;
        const int t0 = w * 32;
        #pragma unroll 4
        for (int t = t0; t < t0 + 32; t++) {
            h2 p = sc[t * 64 + lane];
            float f = (float)p[0];
            bacc = logaddexp2_f(f + bacc, (float)p[1]);
            a += f;
        }
        sa[w * 64 + lane] = a;
        sb[w * 64 + lane] = bacc;
        size_t o = (((size_t)n * NC + c) * 4 + w) * H_DIM + bx * 64 + lane;
        Asub[o] = a;
        Bsub[o] = bacc;
    }
    __syncthreads();

    if (w == 0) {
        float a = sa[lane], b = sb[lane];
        #pragma unroll
        for (int s = 1; s < 4; s++) {
            float as = sa[s * 64 + lane], bs = sb[s * 64 + lane];
            b = logaddexp2_f(as + b, bs);
            a += as;
        }
        size_t o = ((size_t)n * NC + c) * H_DIM + bx * 64 + lane;
        Asum[o] = a;
        Bval[o] = b;
    }
}

// ---------------------------------------------------------------------------
// Kernel 2: sub-chunk replay. Grid (64, 8), 256 threads.
// Block cc: c = cc&31 (low bits -> XCD c%8, SAME XCD whose gemm blocks
// wrote chunk c's plv rows/summaries: gemm linear%8 = by%8 = c%8).
// spair = cc>>5; thread t: s = spair*2 + (t>>7), 4 h-cols = (t&127)*4.
// 4 independent logaddexp2 chains/thread, 16B loads+stores. Carry =
// c chunk folds (4-wide batched) + s sub folds, then 32-t replay.
// BW-bound (~22us floor); serial chain is ~0.5us/block -- don't restructure.
// ---------------------------------------------------------------------------
__global__ __launch_bounds__(256)
void scan_apply(const h2* __restrict__ plv,
                const float* __restrict__ Asum, const float* __restrict__ Bval,
                const float* __restrict__ Asub, const float* __restrict__ Bsub,
                void* __restrict__ outv, const int* __restrict__ flag) {
    const int cc = blockIdx.x;          // 0..63
    const int n = blockIdx.y;
    const int c = cc & 31;
    const int s = (cc >> 5) * 2 + (threadIdx.x >> 7);   // wave-uniform
    const int h0 = (threadIdx.x & 127) * 4;
    const int f32out = *flag;

    float r0 = LOG2_HX0, r1 = r0, r2 = r0, r3 = r0;   // log2(1e-6)
    size_t so = (size_t)n * NC * H_DIM + h0;
    int cp = 0;
    for (; cp + 4 <= c; cp += 4) {
        float4v A0 = *(const float4v*)&Asum[so + (size_t)(cp + 0) * H_DIM];
        float4v B0 = *(const float4v*)&Bval[so + (size_t)(cp + 0) * H_DIM];
        float4v A1 = *(const float4v*)&Asum[so + (size_t)(cp + 1) * H_DIM];
        float4v B1 = *(const float4v*)&Bval[so + (size_t)(cp + 1) * H_DIM];
        float4v A2 = *(const float4v*)&Asum[so + (size_t)(cp + 2) * H_DIM];
        float4v B2 = *(const float4v*)&Bval[so + (size_t)(cp + 2) * H_DIM];
        float4v A3 = *(const float4v*)&Asum[so + (size_t)(cp + 3) * H_DIM];
        float4v B3 = *(const float4v*)&Bval[so + (size_t)(cp + 3) * H_DIM];
        r0 = logaddexp2_f(A0[0] + r0, B0[0]); r1 = logaddexp2_f(A0[1] + r1, B0[1]);
        r2 = logaddexp2_f(A0[2] + r2, B0[2]); r3 = logaddexp2_f(A0[3] + r3, B0[3]);
        r0 = logaddexp2_f(A1[0] + r0, B1[0]); r1 = logaddexp2_f(A1[1] + r1, B1[1]);
        r2 = logaddexp2_f(A1[2] + r2, B1[2]); r3 = logaddexp2_f(A1[3] + r3, B1[3]);
        r0 = logaddexp2_f(A2[0] + r0, B2[0]); r1 = logaddexp2_f(A2[1] + r1, B2[1]);
        r2 = logaddexp2_f(A2[2] + r2, B2[2]); r3 = logaddexp2_f(A2[3] + r3, B2[3]);
        r0 = logaddexp2_f(A3[0] + r0, B3[0]); r1 = logaddexp2_f(A3[1] + r1, B3[1]);
        r2 = logaddexp2_f(A3[2] + r2, B3[2]); r3 = logaddexp2_f(A3[3] + r3, B3[3]);
    }
    for (; cp < c; cp++) {
        float4v A = *(const float4v*)&Asum[so + (size_t)cp * H_DIM];
        float4v B = *(const float4v*)&Bval[so + (size_t)cp * H_DIM];
        r0 = logaddexp2_f(A[0] + r0, B[0]); r1 = logaddexp2_f(A[1] + r1, B[1]);
        r2 = logaddexp2_f(A[2] + r2, B[2]); r3 = logaddexp2_f(A[3] + r3, B[3]);
    }
    size_t sub = (((size_t)n * NC + c) * 4) * H_DIM + h0;
    for (int sp = 0; sp < s; sp++) {
        float4v A = *(const float4v*)&Asub[sub + (size_t)sp * H_DIM];
        float4v B = *(const float4v*)&Bsub[sub + (size_t)sp * H_DIM];
        r0 = logaddexp2_f(A[0] + r0, B[0]); r1 = logaddexp2_f(A[1] + r1, B[1]);
        r2 = logaddexp2_f(A[2] + r2, B[2]); r3 = logaddexp2_f(A[3] + r3, B[3]);
    }

    size_t base = ((size_t)n * LSEQ + (size_t)c * CS + s * 32) * H_DIM + h0;
    if (f32out) {
        float* of = (float*)outv;
        #pragma unroll 4
        for (int t = 0; t < 32; t++) {
            size_t idx = base + (size_t)t * H_DIM;
            h8 p = *(const h8*)&plv[idx];     // (lf0,lv0,lf1,lv1,lf2,lv2,lf3,lv3)
            r0 = logaddexp2_f((float)p[0] + r0, (float)p[1]);
            r1 = logaddexp2_f((float)p[2] + r1, (float)p[3]);
            r2 = logaddexp2_f((float)p[4] + r2, (float)p[5]);
            r3 = logaddexp2_f((float)p[6] + r3, (float)p[7]);
            float4v o4 = {exp2_hw(r0), exp2_hw(r1), exp2_hw(r2), exp2_hw(r3)};
            *(float4v*)&of[idx] = o4;
        }
    } else {
        unsigned int* ob32 = (unsigned int*)outv;
        #pragma unroll 4
        for (int t = 0; t < 32; t++) {
            size_t idx = base + (size_t)t * H_DIM;
            h8 p = *(const h8*)&plv[idx];
            r0 = logaddexp2_f((float)p[0] + r0, (float)p[1]);
            r1 = logaddexp2_f((float)p[2] + r1, (float)p[3]);
            r2 = logaddexp2_f((float)p[4] + r2, (float)p[5]);
            r3 = logaddexp2_f((float)p[6] + r3, (float)p[7]);
            uint2v pk;
            pk[0] = ((unsigned int)f_to_bf16u(exp2_hw(r1)) << 16) | f_to_bf16u(exp2_hw(r0));
            pk[1] = ((unsigned int)f_to_bf16u(exp2_hw(r3)) << 16) | f_to_bf16u(exp2_hw(r2));
            *(uint2v*)&ob32[idx >> 1] = pk;
        }
    }
}

extern "C" void kernel_launch(void* const* d_in, const int* in_sizes, int n_in,
                              void* d_out, int out_size, void* d_ws, size_t ws_size,
                              hipStream_t stream) {
    const void* x = d_in[0];
    const void* W = d_in[1];
    const void* b = d_in[2];

    char* wsb = (char*)d_ws;
    int* flag            = (int*)wsb;                          // 16 B
    float* bconv         = (float*)(wsb + 16);                 // 6 KB
    unsigned short* xc   = (unsigned short*)(wsb + 16384);     // 32 MB
    unsigned short* Wc   = (unsigned short*)(wsb + 16384 + 33554432);  // 1.5 MB
    h2* plv              = (h2*)(wsb + 36700160);              // 64 MB packed (lf,lv)
    float* Asum          = (float*)(wsb + 103809024);          // 512 KB
    float* Bval          = (float*)(wsb + 104333312);          // 512 KB
    float* Asub          = (float*)(wsb + 104857600);          // 2 MB
    float* Bsub          = (float*)(wsb + 106954752);          // 2 MB

    detect_and_bias<<<1, 256, 0, stream>>>((const unsigned short*)x, b, flag, bconv);
    convert_inputs<<<8576, 256, 0, stream>>>(x, W, xc, Wc, flag);

    dim3 g1(M_TOTAL / BM, H_DIM / 64);   // (256, 8): by on x for XCD share
    gemm_gates<<<g1, 256, 0, stream>>>(xc, Wc, bconv, plv, Asum, Bval, Asub, Bsub);

    dim3 g2(NC * 2, NBATCH);             // (64, 8): c in low bits for XCD match
    scan_apply<<<g2, 256, 0, stream>>>(plv, Asum, Bval, Asub, Bsub, d_out, flag);
}

// Round 11
// 214.628 us; speedup vs baseline: 2.5499x; 1.0019x over previous
//
#include <hip/hip_runtime.h>
#include <hip/hip_bf16.h>

// minLSTM: pre = x @ W^T + b (M=32768, N=1536, K=512), log-space gates,
// chunked log-space scan over L=4096 per (n,h), out = exp(log_h).
// ALL log-domain values are in LOG2 units (v_exp/v_log are base-2 native).
// Gate math: sigma-sum identity (3 exp + 4 log per position).
// Pipeline: detect(dtype)+bias -> convert x,W to bf16 -> fused GEMM+gates+
// chunk summaries (8x16-t sub-summaries) -> sub-chunk replay (16 t/block,
// 1024 blocks for 2x scan TLP; scan was latency-bound at 2 blocks/CU).
// GEMM: round-1/5 proven shape (bf16 global_load_lds staging, 40KB LDS,
// 3 blocks/CU), grid (256,8) so all 8 col-blocks of a row-block share one
// XCD L2 (FETCH 133->56MB with convert XCD-affinity remap).
// NOTE: in_sizes/out_size are ELEMENT counts -- dtype is NOT host-derivable;
// the device-side detect kernel is required (round-8 failure).
// FALSIFIED (do not revisit):
//  - rounds 2-4: any fp32-A-in-GEMM staging loses more than 2-pass convert.
//  - rounds 6-7: fused single-pass scan via decoupled lookback; cross-XCD
//    flag spinning collapses memory BW (377us serial, 450us parallel).
//  - round 9: __launch_bounds__(256,4) clamps VGPR to 64 < 96 acc regs ->
//    accumulator spill (870MB WRITE, 345us). (256,3)/84VGPR is the optimum;
//    NEVER raise the occupancy bound on this kernel.

#define H_DIM 512
#define LSEQ 4096
#define NBATCH 8
#define M_TOTAL (NBATCH * LSEQ)  // 32768

#define BM 128
#define BK 64

#define CS 128
#define NC 32            // LSEQ / CS

typedef __attribute__((ext_vector_type(8))) short short8;
typedef __attribute__((ext_vector_type(4))) float floatx4;
typedef __attribute__((ext_vector_type(4))) float float4v;
typedef _Float16 h2 __attribute__((ext_vector_type(2)));
typedef _Float16 h8 __attribute__((ext_vector_type(8)));
typedef __attribute__((ext_vector_type(2))) unsigned int uint2v;

#define NEG_BIG (-1.0e30f)
#define C_LOG2E 1.4426950408889634f
#define LOG2_HX0 (-19.931568569324174f)   // log2(1e-6)

__device__ __forceinline__ float exp2_hw(float x) {
#if __has_builtin(__builtin_amdgcn_exp2f)
    return __builtin_amdgcn_exp2f(x);     // v_exp_f32
#else
    return exp2f(x);
#endif
}

__device__ __forceinline__ float log2_hw(float x) {
#if __has_builtin(__builtin_amdgcn_logf)
    return __builtin_amdgcn_logf(x);      // v_log_f32 (base-2)
#else
    return log2f(x);
#endif
}

// log2(2^p + 2^q), robust for -inf-ish inputs
__device__ __forceinline__ float logaddexp2_f(float p, float q) {
    float m = fmaxf(p, q);
    float d = -fabsf(p - q);
    return m + log2_hw(1.0f + exp2_hw(d));
}

__device__ __forceinline__ float bf16u_to_f(unsigned short u) {
    unsigned int w = ((unsigned int)u) << 16;
    float f;
    __builtin_memcpy(&f, &w, 4);
    return f;
}

__device__ __forceinline__ unsigned short f_to_bf16u(float f) {
    __hip_bfloat16 h = __float2bfloat16(f);
    unsigned short u;
    __builtin_memcpy(&u, &h, 2);
    return u;
}

__device__ __forceinline__ void gload_lds16(const void* g, void* l) {
    __builtin_amdgcn_global_load_lds(
        (const __attribute__((address_space(1))) unsigned int*)g,
        (__attribute__((address_space(3))) unsigned int*)l, 16, 0, 0);
}

// ---------------------------------------------------------------------------
// Kernel 0: dtype detect (single block) + bias -> f32. Vectorized loads.
// fp32 data: low u16 halves uniform -> bf16-NaN exponent P=1/256,
// E[hits in 16384] = 64; bf16 N(0,1) data: 0 hits.
// ---------------------------------------------------------------------------
__global__ void detect_and_bias(const unsigned short* __restrict__ xu,
                                const void* __restrict__ bsrc,
                                int* __restrict__ flag,
                                float* __restrict__ bdst) {
    __shared__ int cnt;
    if (threadIdx.x == 0) cnt = 0;
    __syncthreads();
    const short8* x8 = (const short8*)xu;   // 16384 u16 = 2048 short8
    int local = 0;
    #pragma unroll
    for (int j = 0; j < 8; j++) {
        short8 v = x8[threadIdx.x + j * 256];
        #pragma unroll
        for (int e = 0; e < 8; e++) {
            unsigned short u = (unsigned short)v[e];
            if (((u >> 7) & 0xFF) == 0xFF) local++;
        }
    }
    if (local) atomicAdd(&cnt, local);
    __syncthreads();
    int f = (cnt > 8) ? 1 : 0;
    if (threadIdx.x == 0) flag[0] = f;
    #pragma unroll
    for (int j = 0; j < 6; j++) {
        int i = threadIdx.x + j * 256;
        bdst[i] = f ? ((const float*)bsrc)[i]
                    : bf16u_to_f(((const unsigned short*)bsrc)[i]);
    }
}

// ---------------------------------------------------------------------------
// Kernel 0b: normalize x and W to bf16 (role by block range). Vector loads.
//   [0, 8192) -> x (16777216 elems), [8192, 8576) -> W (786432 elems)
// x-range blocks are REMAPPED for XCD affinity: data block bx covers xc
// rows 4bx..4bx+3, consumed by gemm row-group g=bx>>5 on XCD g%8. Launch
// id l runs on XCD l%8; bijection l->bx ensures g%8 == l%8 so converted
// lines land in the consuming XCD's L2.
// ---------------------------------------------------------------------------
__global__ __launch_bounds__(256)
void convert_inputs(const void* __restrict__ x, const void* __restrict__ W,
                    unsigned short* __restrict__ xc,
                    unsigned short* __restrict__ Wc,
                    const int* __restrict__ flag) {
    const int bid = blockIdx.x;
    const void* src;
    unsigned short* dst;
    int i;
    if (bid < 8192) {
        int b = bid & 7, m = bid >> 3;
        int a = m >> 5, j = m & 31;
        int bx = (((a << 3) + b) << 5) + j;   // row-group 8a+b ≡ bid (mod 8)
        src = x; dst = xc; i = (bx * 256 + threadIdx.x) * 8;
    } else {
        src = W; dst = Wc; i = ((bid - 8192) * 256 + threadIdx.x) * 8;
    }
    if (*flag) {
        const float4v* s4 = (const float4v*)((const float*)src + i);
        float4v a = s4[0], b = s4[1];
        short8 v;
        v[0] = (short)f_to_bf16u(a[0]); v[1] = (short)f_to_bf16u(a[1]);
        v[2] = (short)f_to_bf16u(a[2]); v[3] = (short)f_to_bf16u(a[3]);
        v[4] = (short)f_to_bf16u(b[0]); v[5] = (short)f_to_bf16u(b[1]);
        v[6] = (short)f_to_bf16u(b[2]); v[7] = (short)f_to_bf16u(b[3]);
        *(short8*)&dst[i] = v;
    } else {
        *(short8*)&dst[i] = *(const short8*)&((const short*)src)[i];
    }
}

// ---------------------------------------------------------------------------
// Kernel 1: GEMM + gate math + fused scan summaries (round-5 proven shape).
// Block 256 = 4 waves (2x2). global_load_lds width-16 staging, bf16 inputs.
// LDS XOR swizzle (verified: conflicts ~0). Tail: wave w scans its 32-t
// sub-segment in TWO 16-t halves -> 8 sub-summaries/chunk to Asub/Bsub
// (16-t grain for scan_apply TLP); composed 32-t summary -> LDS; wave 0
// folds 4 -> Asum/Bval.
// Grid (256, 8): by = blockIdx.x so same-by col-blocks share an XCD L2.
// launch_bounds (256,3): 84 VGPR, 3 blocks/CU. DO NOT RAISE (round-9 spill).
// ---------------------------------------------------------------------------
__global__ __launch_bounds__(256, 3)
void gemm_gates(const unsigned short* __restrict__ x,
                const unsigned short* __restrict__ W,
                const float* __restrict__ bias,
                h2* __restrict__ plv,
                float* __restrict__ Asum, float* __restrict__ Bval,
                float* __restrict__ Asub, float* __restrict__ Bsub) {
    __shared__ __align__(16) char ldsbuf[40960];
    short* Alds = (short*)ldsbuf;              // 16 KB during K-loop
    short* Blds = (short*)(ldsbuf + 16384);    // 24 KB during K-loop
    h2* sc = (h2*)ldsbuf;                      // 32 KB after K-loop
    float* sa = (float*)(ldsbuf + 32768);      // 1 KB sub-summary A
    float* sb = sa + 256;                      // 1 KB sub-summary B

    const int by = blockIdx.x;             // row block 0..255 (XCD = by%8)
    const int bx = blockIdx.y;             // col block 0..7 (64 cols/gate)
    const int tid = threadIdx.x;
    const int lane = tid & 63;
    const int w = tid >> 6;
    const int wr = (w >> 1) * 64;
    const int wc2 = w & 1;
    const int l8 = lane >> 3, s8 = lane & 7;
    const int sg = s8 ^ l8;                // swizzled global seg for staging
    const int fr = lane & 15;
    const int q = lane >> 4;

    const int R0 = by * BM;

    floatx4 acc[4][6];
    #pragma unroll
    for (int i = 0; i < 4; i++)
        #pragma unroll
        for (int j = 0; j < 6; j++)
            acc[i][j] = (floatx4){0.f, 0.f, 0.f, 0.f};

    const short* xg = (const short*)x;
    const short* wg = (const short*)W;

    for (int k0 = 0; k0 < H_DIM; k0 += BK) {
        __syncthreads();
        #pragma unroll
        for (int i = 0; i < 4; i++) {
            int c = w * 4 + i;
            const short* g = xg + (size_t)(R0 + c * 8 + l8) * H_DIM + k0 + sg * 8;
            gload_lds16(g, &Alds[c * 512]);
        }
        #pragma unroll
        for (int i = 0; i < 6; i++) {
            int c = w * 6 + i;
            int br = c * 8 + l8;
            int wrow = (br >> 6) * H_DIM + bx * 64 + (br & 63);
            const short* g = wg + (size_t)wrow * H_DIM + k0 + sg * 8;
            gload_lds16(g, &Blds[c * 512]);
        }
        __syncthreads();

        #pragma unroll
        for (int ks = 0; ks < 2; ks++) {
            const int s = ks * 4 + q;
            short8 af[4], bf[6];
            #pragma unroll
            for (int mt = 0; mt < 4; mt++) {
                int ar = wr + mt * 16 + fr;
                af[mt] = *(const short8*)&Alds[ar * BK + ((s ^ (ar & 7)) << 3)];
            }
            #pragma unroll
            for (int j = 0; j < 6; j++) {
                int nt = (j >> 1) * 4 + wc2 * 2 + (j & 1);
                int brr = nt * 16 + fr;
                bf[j] = *(const short8*)&Blds[brr * BK + ((s ^ (brr & 7)) << 3)];
            }
            #pragma unroll
            for (int mt = 0; mt < 4; mt++)
                #pragma unroll
                for (int j = 0; j < 6; j++)
                    acc[mt][j] = __builtin_amdgcn_mfma_f32_16x16x32_bf16(
                        af[mt], bf[j], acc[mt][j], 0, 0, 0);
        }
    }

    __syncthreads();   // staging LDS dead; reuse as sc

    // Epilogue: C/D layout col=lane&15, row=quad*4+reg [m89/m91].
    // sigma-sum form, all in log2 units:
    //   af=1+2^(-f*log2e), ai=1+2^(-i*log2e), s=af+ai
    //   lf = log2(ai)-log2(s); lv = log2(af)-log2(s) + lg
    //   lg = h>=0 ? log2(h+0.5) : -log2(1+2^(-h*log2e))  (argument-select)
    const int rowb = R0 + wr + q * 4;
    const int tloc0 = wr + q * 4;
    #pragma unroll
    for (int jj = 0; jj < 2; jj++) {
        int hl = wc2 * 32 + jj * 16 + fr;
        int hcol = bx * 64 + hl;
        float bfv = bias[hcol];
        float biv = bias[H_DIM + hcol];
        float bhv = bias[2 * H_DIM + hcol];
        float bf2 = -bfv * C_LOG2E;        // fold bias into exp arg via fma
        float bi2 = -biv * C_LOG2E;
        #pragma unroll
        for (int mt = 0; mt < 4; mt++) {
            #pragma unroll
            for (int r = 0; r < 4; r++) {
                float ef = exp2_hw(fminf(fmaf(acc[mt][jj][r], -C_LOG2E, bf2), 126.0f));
                float ei = exp2_hw(fminf(fmaf(acc[mt][2 + jj][r], -C_LOG2E, bi2), 126.0f));
                float hp = acc[mt][4 + jj][r] + bhv;
                float eh = exp2_hw(fminf(-hp * C_LOG2E, 126.0f));
                float afv = 1.0f + ef, aiv = 1.0f + ei;
                float sfi = afv + aiv;
                float ls = log2_hw(sfi);
                float lf = log2_hw(aiv) - ls;                  // log2 f'
                float marg = (hp >= 0.0f) ? (hp + 0.5f) : (1.0f + eh);
                float lm = log2_hw(marg);
                float lg = (hp >= 0.0f) ? lm : -lm;            // log2 g
                float lv = (log2_hw(afv) - ls) + lg;           // log2 (i' g)
                int row = rowb + mt * 16 + r;
                h2 pk;
                pk[0] = (_Float16)lf;
                pk[1] = (_Float16)lv;
                plv[(size_t)row * H_DIM + hcol] = pk;
                sc[(tloc0 + mt * 16 + r) * 64 + hl] = pk;
            }
        }
    }

    __syncthreads();

    const int n = by >> 5, c = by & 31;
    // Wave w scans t in [w*32, w*32+32) for col=lane in TWO 16-t halves.
    // Publish both 16-t summaries (8/chunk) and the composed 32-t summary.
    {
        float a0 = 0.f, b0 = NEG_BIG, a1 = 0.f, b1 = NEG_BIG;
        const int t0 = w * 32;
        #pragma unroll 4
        for (int t = t0; t < t0 + 16; t++) {
            h2 p = sc[t * 64 + lane];
            float f = (float)p[0];
            b0 = logaddexp2_f(f + b0, (float)p[1]);
            a0 += f;
        }
        #pragma unroll 4
        for (int t = t0 + 16; t < t0 + 32; t++) {
            h2 p = sc[t * 64 + lane];
            float f = (float)p[0];
            b1 = logaddexp2_f(f + b1, (float)p[1]);
            a1 += f;
        }
        size_t o8 = (((size_t)n * NC + c) * 8 + w * 2) * H_DIM + bx * 64 + lane;
        Asub[o8] = a0;
        Bsub[o8] = b0;
        Asub[o8 + H_DIM] = a1;
        Bsub[o8 + H_DIM] = b1;
        // composed 32-t transform: T = T1 ∘ T0
        float a = a0 + a1;
        float bacc = logaddexp2_f(a1 + b0, b1);
        sa[w * 64 + lane] = a;
        sb[w * 64 + lane] = bacc;
    }
    __syncthreads();

    if (w == 0) {
        float a = sa[lane], b = sb[lane];
        #pragma unroll
        for (int s = 1; s < 4; s++) {
            float as = sa[s * 64 + lane], bs = sb[s * 64 + lane];
            b = logaddexp2_f(as + b, bs);
            a += as;
        }
        size_t o = ((size_t)n * NC + c) * H_DIM + bx * 64 + lane;
        Asum[o] = a;
        Bval[o] = b;
    }
}

// ---------------------------------------------------------------------------
// Kernel 2: sub-chunk replay at 16-t grain. Grid (128, 8), 256 threads.
// Block cc: c = cc&31 (low bits -> XCD c%8, SAME XCD whose gemm blocks
// wrote chunk c's plv rows/summaries). spair = cc>>5 in 0..3;
// thread t: s = spair*2 + (t>>7) in 0..7, 4 h-cols = (t&127)*4.
// 1024 blocks = 4/CU (2x the 32-t version's TLP; scan was latency-bound).
// Carry = c chunk folds (4-wide batched) + <=7 sub folds, then 16-t replay.
// ---------------------------------------------------------------------------
__global__ __launch_bounds__(256)
void scan_apply(const h2* __restrict__ plv,
                const float* __restrict__ Asum, const float* __restrict__ Bval,
                const float* __restrict__ Asub, const float* __restrict__ Bsub,
                void* __restrict__ outv, const int* __restrict__ flag) {
    const int cc = blockIdx.x;          // 0..127
    const int n = blockIdx.y;
    const int c = cc & 31;
    const int s = (cc >> 5) * 2 + (threadIdx.x >> 7);   // wave-uniform 0..7
    const int h0 = (threadIdx.x & 127) * 4;
    const int f32out = *flag;

    float r0 = LOG2_HX0, r1 = r0, r2 = r0, r3 = r0;   // log2(1e-6)
    size_t so = (size_t)n * NC * H_DIM + h0;
    int cp = 0;
    for (; cp + 4 <= c; cp += 4) {
        float4v A0 = *(const float4v*)&Asum[so + (size_t)(cp + 0) * H_DIM];
        float4v B0 = *(const float4v*)&Bval[so + (size_t)(cp + 0) * H_DIM];
        float4v A1 = *(const float4v*)&Asum[so + (size_t)(cp + 1) * H_DIM];
        float4v B1 = *(const float4v*)&Bval[so + (size_t)(cp + 1) * H_DIM];
        float4v A2 = *(const float4v*)&Asum[so + (size_t)(cp + 2) * H_DIM];
        float4v B2 = *(const float4v*)&Bval[so + (size_t)(cp + 2) * H_DIM];
        float4v A3 = *(const float4v*)&Asum[so + (size_t)(cp + 3) * H_DIM];
        float4v B3 = *(const float4v*)&Bval[so + (size_t)(cp + 3) * H_DIM];
        r0 = logaddexp2_f(A0[0] + r0, B0[0]); r1 = logaddexp2_f(A0[1] + r1, B0[1]);
        r2 = logaddexp2_f(A0[2] + r2, B0[2]); r3 = logaddexp2_f(A0[3] + r3, B0[3]);
        r0 = logaddexp2_f(A1[0] + r0, B1[0]); r1 = logaddexp2_f(A1[1] + r1, B1[1]);
        r2 = logaddexp2_f(A1[2] + r2, B1[2]); r3 = logaddexp2_f(A1[3] + r3, B1[3]);
        r0 = logaddexp2_f(A2[0] + r0, B2[0]); r1 = logaddexp2_f(A2[1] + r1, B2[1]);
        r2 = logaddexp2_f(A2[2] + r2, B2[2]); r3 = logaddexp2_f(A2[3] + r3, B2[3]);
        r0 = logaddexp2_f(A3[0] + r0, B3[0]); r1 = logaddexp2_f(A3[1] + r1, B3[1]);
        r2 = logaddexp2_f(A3[2] + r2, B3[2]); r3 = logaddexp2_f(A3[3] + r3, B3[3]);
    }
    for (; cp < c; cp++) {
        float4v A = *(const float4v*)&Asum[so + (size_t)cp * H_DIM];
        float4v B = *(const float4v*)&Bval[so + (size_t)cp * H_DIM];
        r0 = logaddexp2_f(A[0] + r0, B[0]); r1 = logaddexp2_f(A[1] + r1, B[1]);
        r2 = logaddexp2_f(A[2] + r2, B[2]); r3 = logaddexp2_f(A[3] + r3, B[3]);
    }
    size_t sub = (((size_t)n * NC + c) * 8) * H_DIM + h0;
    for (int sp = 0; sp < s; sp++) {
        float4v A = *(const float4v*)&Asub[sub + (size_t)sp * H_DIM];
        float4v B = *(const float4v*)&Bsub[sub + (size_t)sp * H_DIM];
        r0 = logaddexp2_f(A[0] + r0, B[0]); r1 = logaddexp2_f(A[1] + r1, B[1]);
        r2 = logaddexp2_f(A[2] + r2, B[2]); r3 = logaddexp2_f(A[3] + r3, B[3]);
    }

    size_t base = ((size_t)n * LSEQ + (size_t)c * CS + s * 16) * H_DIM + h0;
    if (f32out) {
        float* of = (float*)outv;
        #pragma unroll 4
        for (int t = 0; t < 16; t++) {
            size_t idx = base + (size_t)t * H_DIM;
            h8 p = *(const h8*)&plv[idx];     // (lf0,lv0,lf1,lv1,lf2,lv2,lf3,lv3)
            r0 = logaddexp2_f((float)p[0] + r0, (float)p[1]);
            r1 = logaddexp2_f((float)p[2] + r1, (float)p[3]);
            r2 = logaddexp2_f((float)p[4] + r2, (float)p[5]);
            r3 = logaddexp2_f((float)p[6] + r3, (float)p[7]);
            float4v o4 = {exp2_hw(r0), exp2_hw(r1), exp2_hw(r2), exp2_hw(r3)};
            *(float4v*)&of[idx] = o4;
        }
    } else {
        unsigned int* ob32 = (unsigned int*)outv;
        #pragma unroll 4
        for (int t = 0; t < 16; t++) {
            size_t idx = base + (size_t)t * H_DIM;
            h8 p = *(const h8*)&plv[idx];
            r0 = logaddexp2_f((float)p[0] + r0, (float)p[1]);
            r1 = logaddexp2_f((float)p[2] + r1, (float)p[3]);
            r2 = logaddexp2_f((float)p[4] + r2, (float)p[5]);
            r3 = logaddexp2_f((float)p[6] + r3, (float)p[7]);
            uint2v pk;
            pk[0] = ((unsigned int)f_to_bf16u(exp2_hw(r1)) << 16) | f_to_bf16u(exp2_hw(r0));
            pk[1] = ((unsigned int)f_to_bf16u(exp2_hw(r3)) << 16) | f_to_bf16u(exp2_hw(r2));
            *(uint2v*)&ob32[idx >> 1] = pk;
        }
    }
}

extern "C" void kernel_launch(void* const* d_in, const int* in_sizes, int n_in,
                              void* d_out, int out_size, void* d_ws, size_t ws_size,
                              hipStream_t stream) {
    const void* x = d_in[0];
    const void* W = d_in[1];
    const void* b = d_in[2];

    char* wsb = (char*)d_ws;
    int* flag            = (int*)wsb;                          // 16 B
    float* bconv         = (float*)(wsb + 16);                 // 6 KB
    unsigned short* xc   = (unsigned short*)(wsb + 16384);     // 32 MB
    unsigned short* Wc   = (unsigned short*)(wsb + 16384 + 33554432);  // 1.5 MB
    h2* plv              = (h2*)(wsb + 36700160);              // 64 MB packed (lf,lv)
    float* Asum          = (float*)(wsb + 103809024);          // 512 KB
    float* Bval          = (float*)(wsb + 104333312);          // 512 KB
    float* Asub          = (float*)(wsb + 104857600);          // 4 MB (8 subs/chunk)
    float* Bsub          = (float*)(wsb + 109051904);          // 4 MB

    detect_and_bias<<<1, 256, 0, stream>>>((const unsigned short*)x, b, flag, bconv);
    convert_inputs<<<8576, 256, 0, stream>>>(x, W, xc, Wc, flag);

    dim3 g1(M_TOTAL / BM, H_DIM / 64);   // (256, 8): by on x for XCD share
    gemm_gates<<<g1, 256, 0, stream>>>(xc, Wc, bconv, plv, Asum, Bval, Asub, Bsub);

    dim3 g2(NC * 4, NBATCH);             // (128, 8): c in low bits for XCD match
    scan_apply<<<g2, 256, 0, stream>>>(plv, Asum, Bval, Asub, Bsub, d_out, flag);
}

// Round 13
// 214.448 us; speedup vs baseline: 2.5520x; 1.0008x over previous
//
#include <hip/hip_runtime.h>
#include <hip/hip_bf16.h>

// minLSTM: pre = x @ W^T + b (M=32768, N=1536, K=512), log-space gates,
// chunked log-space scan over L=4096 per (n,h), out = exp(log_h).
// ALL log-domain values are in LOG2 units (v_exp/v_log are base-2 native).
// Gate math: sigma-sum identity (3 exp + 4 log per position).
// Pipeline (3 kernels): convert x,W->bf16 (with per-block self-detect of
// dtype from the SAME first-32KB header -> deterministic agreement; bias +
// flag by last block) -> fused GEMM+gates+chunk summaries -> sub-chunk
// replay. GEMM: proven shape (bf16 global_load_lds staging, 40KB LDS,
// 3 blocks/CU), grid (256,8) so all 8 col-blocks of a row-block share one
// XCD L2 (FETCH 133->56MB with convert XCD-affinity remap).
// NOTE: in_sizes/out_size are ELEMENT counts -- dtype is NOT host-derivable
// (round-8 failure); device-side detection is required.
// Round-12 bench was an infrastructure failure (container died twice);
// kernel re-audited (bounds, no spins, no capture violations) and resubmitted.
// FALSIFIED (do not revisit):
//  - rounds 2-4: any fp32-A-in-GEMM staging loses more than 2-pass convert.
//  - rounds 6-7: fused single-pass scan via decoupled lookback; cross-XCD
//    flag spinning collapses memory BW (377us serial, 450us parallel).
//  - round 9: __launch_bounds__(256,4) clamps VGPR to 64 < 96 acc regs ->
//    accumulator spill (870MB WRITE, 345us). (256,3)/84VGPR is the optimum.
//  - rounds 5/10/11: scan_apply restructures (col-width, XCD-match, 16-t
//    grain/2x TLP) all neutral within +-4us -- scan is at its floor.

#define H_DIM 512
#define LSEQ 4096
#define NBATCH 8
#define M_TOTAL (NBATCH * LSEQ)  // 32768

#define BM 128
#define BK 64

#define CS 128
#define NC 32            // LSEQ / CS

typedef __attribute__((ext_vector_type(8))) short short8;
typedef __attribute__((ext_vector_type(4))) float floatx4;
typedef __attribute__((ext_vector_type(4))) float float4v;
typedef _Float16 h2 __attribute__((ext_vector_type(2)));
typedef _Float16 h8 __attribute__((ext_vector_type(8)));
typedef __attribute__((ext_vector_type(2))) unsigned int uint2v;

#define NEG_BIG (-1.0e30f)
#define C_LOG2E 1.4426950408889634f
#define LOG2_HX0 (-19.931568569324174f)   // log2(1e-6)

__device__ __forceinline__ float exp2_hw(float x) {
#if __has_builtin(__builtin_amdgcn_exp2f)
    return __builtin_amdgcn_exp2f(x);     // v_exp_f32
#else
    return exp2f(x);
#endif
}

__device__ __forceinline__ float log2_hw(float x) {
#if __has_builtin(__builtin_amdgcn_logf)
    return __builtin_amdgcn_logf(x);      // v_log_f32 (base-2)
#else
    return log2f(x);
#endif
}

// log2(2^p + 2^q), robust for -inf-ish inputs
__device__ __forceinline__ float logaddexp2_f(float p, float q) {
    float m = fmaxf(p, q);
    float d = -fabsf(p - q);
    return m + log2_hw(1.0f + exp2_hw(d));
}

__device__ __forceinline__ float bf16u_to_f(unsigned short u) {
    unsigned int w = ((unsigned int)u) << 16;
    float f;
    __builtin_memcpy(&f, &w, 4);
    return f;
}

__device__ __forceinline__ unsigned short f_to_bf16u(float f) {
    __hip_bfloat16 h = __float2bfloat16(f);
    unsigned short u;
    __builtin_memcpy(&u, &h, 2);
    return u;
}

__device__ __forceinline__ void gload_lds16(const void* g, void* l) {
    __builtin_amdgcn_global_load_lds(
        (const __attribute__((address_space(1))) unsigned int*)g,
        (__attribute__((address_space(3))) unsigned int*)l, 16, 0, 0);
}

// ---------------------------------------------------------------------------
// Kernel 0: normalize inputs, with per-block dtype self-detection.
// Detection: every block scans the SAME first 16384 u16 (32 KB) of x with
// the SAME threshold -> every block computes the identical flag value
// (deterministic agreement, no cross-block sync). fp32 data: low u16
// halves ~uniform -> bf16-NaN-exponent rate 1/256, E[hits]=32; bf16 N(0,1)
// data: 0 hits. Header reads are L2-broadcast (~2us aggregate).
// Block roles (2145 blocks x 256 thr, 32 elems/thread):
//   [0, 2048)    : x convert, XCD-affinity remap (16 xc rows/block; the
//                  bijection keeps producer XCD == gemm consumer XCD)
//   [2048, 2144) : W convert (8192 elems/block)
//   2144         : bias -> f32 + publish flag for scan_apply
// ---------------------------------------------------------------------------
__global__ __launch_bounds__(256)
void convert_inputs(const void* __restrict__ x, const void* __restrict__ W,
                    const void* __restrict__ bsrc,
                    unsigned short* __restrict__ xc,
                    unsigned short* __restrict__ Wc,
                    float* __restrict__ bconv,
                    int* __restrict__ flagw) {
    __shared__ int cnt;
    if (threadIdx.x == 0) cnt = 0;
    __syncthreads();
    {
        const short8* hx = (const short8*)x;   // first 2048 short8 = 32 KB
        int local = 0;
        #pragma unroll
        for (int j = 0; j < 8; j++) {
            short8 v = hx[threadIdx.x + j * 256];
            #pragma unroll
            for (int e = 0; e < 8; e++) {
                unsigned short u = (unsigned short)v[e];
                if (((u >> 7) & 0xFF) == 0xFF) local++;
            }
        }
        if (local) atomicAdd(&cnt, local);
    }
    __syncthreads();
    const int f32in = (cnt > 8) ? 1 : 0;

    const int bid = blockIdx.x;
    if (bid < 2048) {
        // XCD-affinity bijection: i/8 == row-group G, G%8 == bid%8 == XCD
        int b = bid & 7, rest = bid >> 3;
        int G = b + 8 * (rest & 31);
        int r = rest >> 5;
        int i = G * 8 + r;                 // data block in [0,2048)
        int base = i * 8192 + threadIdx.x * 8;
        #pragma unroll
        for (int j = 0; j < 4; j++) {
            int idx = base + j * 2048;
            if (f32in) {
                const float4v* s4 = (const float4v*)((const float*)x + idx);
                float4v a = s4[0], bb = s4[1];
                short8 v;
                v[0] = (short)f_to_bf16u(a[0]);  v[1] = (short)f_to_bf16u(a[1]);
                v[2] = (short)f_to_bf16u(a[2]);  v[3] = (short)f_to_bf16u(a[3]);
                v[4] = (short)f_to_bf16u(bb[0]); v[5] = (short)f_to_bf16u(bb[1]);
                v[6] = (short)f_to_bf16u(bb[2]); v[7] = (short)f_to_bf16u(bb[3]);
                *(short8*)&xc[idx] = v;
            } else {
                *(short8*)&xc[idx] = *(const short8*)&((const short*)x)[idx];
            }
        }
    } else if (bid < 2144) {
        int base = (bid - 2048) * 8192 + threadIdx.x * 8;
        #pragma unroll
        for (int j = 0; j < 4; j++) {
            int idx = base + j * 2048;
            if (f32in) {
                const float4v* s4 = (const float4v*)((const float*)W + idx);
                float4v a = s4[0], bb = s4[1];
                short8 v;
                v[0] = (short)f_to_bf16u(a[0]);  v[1] = (short)f_to_bf16u(a[1]);
                v[2] = (short)f_to_bf16u(a[2]);  v[3] = (short)f_to_bf16u(a[3]);
                v[4] = (short)f_to_bf16u(bb[0]); v[5] = (short)f_to_bf16u(bb[1]);
                v[6] = (short)f_to_bf16u(bb[2]); v[7] = (short)f_to_bf16u(bb[3]);
                *(short8*)&Wc[idx] = v;
            } else {
                *(short8*)&Wc[idx] = *(const short8*)&((const short*)W)[idx];
            }
        }
    } else {
        #pragma unroll
        for (int j = 0; j < 6; j++) {
            int i = threadIdx.x + j * 256;
            bconv[i] = f32in ? ((const float*)bsrc)[i]
                             : bf16u_to_f(((const unsigned short*)bsrc)[i]);
        }
        if (threadIdx.x == 0) flagw[0] = f32in;   // for scan_apply
    }
}

// ---------------------------------------------------------------------------
// Kernel 1: GEMM + gate math + fused scan summaries (proven shape).
// Block 256 = 4 waves (2x2). global_load_lds width-16 staging, bf16 inputs.
// LDS XOR swizzle (verified: conflicts ~0). Tail: wave w scans its 32-t
// sub-segment in TWO 16-t halves -> 8 sub-summaries/chunk to Asub/Bsub;
// composed 32-t summary -> LDS; wave 0 folds 4 -> Asum/Bval.
// Grid (256, 8): by = blockIdx.x so same-by col-blocks share an XCD L2.
// launch_bounds (256,3): 84 VGPR, 3 blocks/CU. DO NOT RAISE (round-9 spill).
// ---------------------------------------------------------------------------
__global__ __launch_bounds__(256, 3)
void gemm_gates(const unsigned short* __restrict__ x,
                const unsigned short* __restrict__ W,
                const float* __restrict__ bias,
                h2* __restrict__ plv,
                float* __restrict__ Asum, float* __restrict__ Bval,
                float* __restrict__ Asub, float* __restrict__ Bsub) {
    __shared__ __align__(16) char ldsbuf[40960];
    short* Alds = (short*)ldsbuf;              // 16 KB during K-loop
    short* Blds = (short*)(ldsbuf + 16384);    // 24 KB during K-loop
    h2* sc = (h2*)ldsbuf;                      // 32 KB after K-loop
    float* sa = (float*)(ldsbuf + 32768);      // 1 KB sub-summary A
    float* sb = sa + 256;                      // 1 KB sub-summary B

    const int by = blockIdx.x;             // row block 0..255 (XCD = by%8)
    const int bx = blockIdx.y;             // col block 0..7 (64 cols/gate)
    const int tid = threadIdx.x;
    const int lane = tid & 63;
    const int w = tid >> 6;
    const int wr = (w >> 1) * 64;
    const int wc2 = w & 1;
    const int l8 = lane >> 3, s8 = lane & 7;
    const int sg = s8 ^ l8;                // swizzled global seg for staging
    const int fr = lane & 15;
    const int q = lane >> 4;

    const int R0 = by * BM;

    floatx4 acc[4][6];
    #pragma unroll
    for (int i = 0; i < 4; i++)
        #pragma unroll
        for (int j = 0; j < 6; j++)
            acc[i][j] = (floatx4){0.f, 0.f, 0.f, 0.f};

    const short* xg = (const short*)x;
    const short* wg = (const short*)W;

    for (int k0 = 0; k0 < H_DIM; k0 += BK) {
        __syncthreads();
        #pragma unroll
        for (int i = 0; i < 4; i++) {
            int c = w * 4 + i;
            const short* g = xg + (size_t)(R0 + c * 8 + l8) * H_DIM + k0 + sg * 8;
            gload_lds16(g, &Alds[c * 512]);
        }
        #pragma unroll
        for (int i = 0; i < 6; i++) {
            int c = w * 6 + i;
            int br = c * 8 + l8;
            int wrow = (br >> 6) * H_DIM + bx * 64 + (br & 63);
            const short* g = wg + (size_t)wrow * H_DIM + k0 + sg * 8;
            gload_lds16(g, &Blds[c * 512]);
        }
        __syncthreads();

        #pragma unroll
        for (int ks = 0; ks < 2; ks++) {
            const int s = ks * 4 + q;
            short8 af[4], bf[6];
            #pragma unroll
            for (int mt = 0; mt < 4; mt++) {
                int ar = wr + mt * 16 + fr;
                af[mt] = *(const short8*)&Alds[ar * BK + ((s ^ (ar & 7)) << 3)];
            }
            #pragma unroll
            for (int j = 0; j < 6; j++) {
                int nt = (j >> 1) * 4 + wc2 * 2 + (j & 1);
                int brr = nt * 16 + fr;
                bf[j] = *(const short8*)&Blds[brr * BK + ((s ^ (brr & 7)) << 3)];
            }
            #pragma unroll
            for (int mt = 0; mt < 4; mt++)
                #pragma unroll
                for (int j = 0; j < 6; j++)
                    acc[mt][j] = __builtin_amdgcn_mfma_f32_16x16x32_bf16(
                        af[mt], bf[j], acc[mt][j], 0, 0, 0);
        }
    }

    __syncthreads();   // staging LDS dead; reuse as sc

    // Epilogue: C/D layout col=lane&15, row=quad*4+reg [m89/m91].
    // sigma-sum form, all in log2 units:
    //   af=1+2^(-f*log2e), ai=1+2^(-i*log2e), s=af+ai
    //   lf = log2(ai)-log2(s); lv = log2(af)-log2(s) + lg
    //   lg = h>=0 ? log2(h+0.5) : -log2(1+2^(-h*log2e))  (argument-select)
    const int rowb = R0 + wr + q * 4;
    const int tloc0 = wr + q * 4;
    #pragma unroll
    for (int jj = 0; jj < 2; jj++) {
        int hl = wc2 * 32 + jj * 16 + fr;
        int hcol = bx * 64 + hl;
        float bfv = bias[hcol];
        float biv = bias[H_DIM + hcol];
        float bhv = bias[2 * H_DIM + hcol];
        float bf2 = -bfv * C_LOG2E;        // fold bias into exp arg via fma
        float bi2 = -biv * C_LOG2E;
        #pragma unroll
        for (int mt = 0; mt < 4; mt++) {
            #pragma unroll
            for (int r = 0; r < 4; r++) {
                float ef = exp2_hw(fminf(fmaf(acc[mt][jj][r], -C_LOG2E, bf2), 126.0f));
                float ei = exp2_hw(fminf(fmaf(acc[mt][2 + jj][r], -C_LOG2E, bi2), 126.0f));
                float hp = acc[mt][4 + jj][r] + bhv;
                float eh = exp2_hw(fminf(-hp * C_LOG2E, 126.0f));
                float afv = 1.0f + ef, aiv = 1.0f + ei;
                float sfi = afv + aiv;
                float ls = log2_hw(sfi);
                float lf = log2_hw(aiv) - ls;                  // log2 f'
                float marg = (hp >= 0.0f) ? (hp + 0.5f) : (1.0f + eh);
                float lm = log2_hw(marg);
                float lg = (hp >= 0.0f) ? lm : -lm;            // log2 g
                float lv = (log2_hw(afv) - ls) + lg;           // log2 (i' g)
                int row = rowb + mt * 16 + r;
                h2 pk;
                pk[0] = (_Float16)lf;
                pk[1] = (_Float16)lv;
                plv[(size_t)row * H_DIM + hcol] = pk;
                sc[(tloc0 + mt * 16 + r) * 64 + hl] = pk;
            }
        }
    }

    __syncthreads();

    const int n = by >> 5, c = by & 31;
    // Wave w scans t in [w*32, w*32+32) for col=lane in TWO 16-t halves.
    // Publish both 16-t summaries (8/chunk) and the composed 32-t summary.
    {
        float a0 = 0.f, b0 = NEG_BIG, a1 = 0.f, b1 = NEG_BIG;
        const int t0 = w * 32;
        #pragma unroll 4
        for (int t = t0; t < t0 + 16; t++) {
            h2 p = sc[t * 64 + lane];
            float f = (float)p[0];
            b0 = logaddexp2_f(f + b0, (float)p[1]);
            a0 += f;
        }
        #pragma unroll 4
        for (int t = t0 + 16; t < t0 + 32; t++) {
            h2 p = sc[t * 64 + lane];
            float f = (float)p[0];
            b1 = logaddexp2_f(f + b1, (float)p[1]);
            a1 += f;
        }
        size_t o8 = (((size_t)n * NC + c) * 8 + w * 2) * H_DIM + bx * 64 + lane;
        Asub[o8] = a0;
        Bsub[o8] = b0;
        Asub[o8 + H_DIM] = a1;
        Bsub[o8 + H_DIM] = b1;
        // composed 32-t transform: T = T1 ∘ T0
        float a = a0 + a1;
        float bacc = logaddexp2_f(a1 + b0, b1);
        sa[w * 64 + lane] = a;
        sb[w * 64 + lane] = bacc;
    }
    __syncthreads();

    if (w == 0) {
        float a = sa[lane], b = sb[lane];
        #pragma unroll
        for (int s = 1; s < 4; s++) {
            float as = sa[s * 64 + lane], bs = sb[s * 64 + lane];
            b = logaddexp2_f(as + b, bs);
            a += as;
        }
        size_t o = ((size_t)n * NC + c) * H_DIM + bx * 64 + lane;
        Asum[o] = a;
        Bval[o] = b;
    }
}

// ---------------------------------------------------------------------------
// Kernel 2: sub-chunk replay at 16-t grain. Grid (128, 8), 256 threads.
// Block cc: c = cc&31 (low bits -> XCD c%8, SAME XCD whose gemm blocks
// wrote chunk c's plv rows/summaries). spair = cc>>5 in 0..3;
// thread t: s = spair*2 + (t>>7) in 0..7, 4 h-cols = (t&127)*4.
// Carry = c chunk folds (4-wide batched) + <=7 sub folds, then 16-t replay.
// At its floor per rounds 5/10/11 -- do not restructure further.
// ---------------------------------------------------------------------------
__global__ __launch_bounds__(256)
void scan_apply(const h2* __restrict__ plv,
                const float* __restrict__ Asum, const float* __restrict__ Bval,
                const float* __restrict__ Asub, const float* __restrict__ Bsub,
                void* __restrict__ outv, const int* __restrict__ flag) {
    const int cc = blockIdx.x;          // 0..127
    const int n = blockIdx.y;
    const int c = cc & 31;
    const int s = (cc >> 5) * 2 + (threadIdx.x >> 7);   // wave-uniform 0..7
    const int h0 = (threadIdx.x & 127) * 4;
    const int f32out = *flag;

    float r0 = LOG2_HX0, r1 = r0, r2 = r0, r3 = r0;   // log2(1e-6)
    size_t so = (size_t)n * NC * H_DIM + h0;
    int cp = 0;
    for (; cp + 4 <= c; cp += 4) {
        float4v A0 = *(const float4v*)&Asum[so + (size_t)(cp + 0) * H_DIM];
        float4v B0 = *(const float4v*)&Bval[so + (size_t)(cp + 0) * H_DIM];
        float4v A1 = *(const float4v*)&Asum[so + (size_t)(cp + 1) * H_DIM];
        float4v B1 = *(const float4v*)&Bval[so + (size_t)(cp + 1) * H_DIM];
        float4v A2 = *(const float4v*)&Asum[so + (size_t)(cp + 2) * H_DIM];
        float4v B2 = *(const float4v*)&Bval[so + (size_t)(cp + 2) * H_DIM];
        float4v A3 = *(const float4v*)&Asum[so + (size_t)(cp + 3) * H_DIM];
        float4v B3 = *(const float4v*)&Bval[so + (size_t)(cp + 3) * H_DIM];
        r0 = logaddexp2_f(A0[0] + r0, B0[0]); r1 = logaddexp2_f(A0[1] + r1, B0[1]);
        r2 = logaddexp2_f(A0[2] + r2, B0[2]); r3 = logaddexp2_f(A0[3] + r3, B0[3]);
        r0 = logaddexp2_f(A1[0] + r0, B1[0]); r1 = logaddexp2_f(A1[1] + r1, B1[1]);
        r2 = logaddexp2_f(A1[2] + r2, B1[2]); r3 = logaddexp2_f(A1[3] + r3, B1[3]);
        r0 = logaddexp2_f(A2[0] + r0, B2[0]); r1 = logaddexp2_f(A2[1] + r1, B2[1]);
        r2 = logaddexp2_f(A2[2] + r2, B2[2]); r3 = logaddexp2_f(A2[3] + r3, B2[3]);
        r0 = logaddexp2_f(A3[0] + r0, B3[0]); r1 = logaddexp2_f(A3[1] + r1, B3[1]);
        r2 = logaddexp2_f(A3[2] + r2, B3[2]); r3 = logaddexp2_f(A3[3] + r3, B3[3]);
    }
    for (; cp < c; cp++) {
        float4v A = *(const float4v*)&Asum[so + (size_t)cp * H_DIM];
        float4v B = *(const float4v*)&Bval[so + (size_t)cp * H_DIM];
        r0 = logaddexp2_f(A[0] + r0, B[0]); r1 = logaddexp2_f(A[1] + r1, B[1]);
        r2 = logaddexp2_f(A[2] + r2, B[2]); r3 = logaddexp2_f(A[3] + r3, B[3]);
    }
    size_t sub = (((size_t)n * NC + c) * 8) * H_DIM + h0;
    for (int sp = 0; sp < s; sp++) {
        float4v A = *(const float4v*)&Asub[sub + (size_t)sp * H_DIM];
        float4v B = *(const float4v*)&Bsub[sub + (size_t)sp * H_DIM];
        r0 = logaddexp2_f(A[0] + r0, B[0]); r1 = logaddexp2_f(A[1] + r1, B[1]);
        r2 = logaddexp2_f(A[2] + r2, B[2]); r3 = logaddexp2_f(A[3] + r3, B[3]);
    }

    size_t base = ((size_t)n * LSEQ + (size_t)c * CS + s * 16) * H_DIM + h0;
    if (f32out) {
        float* of = (float*)outv;
        #pragma unroll 4
        for (int t = 0; t < 16; t++) {
            size_t idx = base + (size_t)t * H_DIM;
            h8 p = *(const h8*)&plv[idx];     // (lf0,lv0,lf1,lv1,lf2,lv2,lf3,lv3)
            r0 = logaddexp2_f((float)p[0] + r0, (float)p[1]);
            r1 = logaddexp2_f((float)p[2] + r1, (float)p[3]);
            r2 = logaddexp2_f((float)p[4] + r2, (float)p[5]);
            r3 = logaddexp2_f((float)p[6] + r3, (float)p[7]);
            float4v o4 = {exp2_hw(r0), exp2_hw(r1), exp2_hw(r2), exp2_hw(r3)};
            *(float4v*)&of[idx] = o4;
        }
    } else {
        unsigned int* ob32 = (unsigned int*)outv;
        #pragma unroll 4
        for (int t = 0; t < 16; t++) {
            size_t idx = base + (size_t)t * H_DIM;
            h8 p = *(const h8*)&plv[idx];
            r0 = logaddexp2_f((float)p[0] + r0, (float)p[1]);
            r1 = logaddexp2_f((float)p[2] + r1, (float)p[3]);
            r2 = logaddexp2_f((float)p[4] + r2, (float)p[5]);
            r3 = logaddexp2_f((float)p[6] + r3, (float)p[7]);
            uint2v pk;
            pk[0] = ((unsigned int)f_to_bf16u(exp2_hw(r1)) << 16) | f_to_bf16u(exp2_hw(r0));
            pk[1] = ((unsigned int)f_to_bf16u(exp2_hw(r3)) << 16) | f_to_bf16u(exp2_hw(r2));
            *(uint2v*)&ob32[idx >> 1] = pk;
        }
    }
}

extern "C" void kernel_launch(void* const* d_in, const int* in_sizes, int n_in,
                              void* d_out, int out_size, void* d_ws, size_t ws_size,
                              hipStream_t stream) {
    const void* x = d_in[0];
    const void* W = d_in[1];
    const void* b = d_in[2];

    char* wsb = (char*)d_ws;
    int* flag            = (int*)wsb;                          // 16 B
    float* bconv         = (float*)(wsb + 16);                 // 6 KB
    unsigned short* xc   = (unsigned short*)(wsb + 16384);     // 32 MB
    unsigned short* Wc   = (unsigned short*)(wsb + 16384 + 33554432);  // 1.5 MB
    h2* plv              = (h2*)(wsb + 36700160);              // 64 MB packed (lf,lv)
    float* Asum          = (float*)(wsb + 103809024);          // 512 KB
    float* Bval          = (float*)(wsb + 104333312);          // 512 KB
    float* Asub          = (float*)(wsb + 104857600);          // 4 MB (8 subs/chunk)
    float* Bsub          = (float*)(wsb + 109051904);          // 4 MB

    convert_inputs<<<2145, 256, 0, stream>>>(x, W, b, xc, Wc, bconv, flag);

    dim3 g1(M_TOTAL / BM, H_DIM / 64);   // (256, 8): by on x for XCD share
    gemm_gates<<<g1, 256, 0, stream>>>(xc, Wc, bconv, plv, Asum, Bval, Asub, Bsub);

    dim3 g2(NC * 4, NBATCH);             // (128, 8): c in low bits for XCD match
    scan_apply<<<g2, 256, 0, stream>>>(plv, Asum, Bval, Asub, Bsub, d_out, flag);
}